// Round 7
// baseline (553.660 us; speedup 1.0000x reference)
//
#include <hip/hip_runtime.h>
#include <hip/hip_bf16.h>

#define N_ENT_C   100000
#define N_EDGE_C  500000
#define N_SEED_C  10000
#define DIM_C     128

#define N2_C      (2 * N_ENT_C)     // concat rows (both graphs)
#define NBKT      391               // ceil(N2 / 512)
#define BKT_CAP   8192              // entries per bucket (mean 5120, 43 sigma safe)
#define EPB       2048              // edges per block in phase A (490 blocks)

typedef unsigned int   u32;
typedef unsigned short u16;
typedef __attribute__((ext_vector_type(8))) short bf16x8;
typedef __attribute__((ext_vector_type(4))) float f32x4;

__device__ __forceinline__ float bflo(u32 v) { return __uint_as_float(v << 16); }
__device__ __forceinline__ float bfhi(u32 v) { return __uint_as_float(v & 0xFFFF0000u); }
__device__ __forceinline__ u16 f2bf(float f) {       // RNE
  u32 u = __float_as_uint(f);
  u += 0x7FFFu + ((u >> 16) & 1u);
  return (u16)(u >> 16);
}

// Detect fp32 vs packed bf16 input; also zero the bucket counters.
__global__ void k_detect(const u32* __restrict__ words, int* __restrict__ flag,
                         int* __restrict__ bkt_cnt) {
  int tid = threadIdx.x;
  bkt_cnt[tid] = 0;
  bkt_cnt[tid + 256] = 0;
  if (tid == 0) {
    int cnt = 0;
    for (int i = 0; i < 64; ++i) {
      u32 e = (words[i] >> 7) & 0xFF;
      cnt += (e < 96) ? 1 : 0;
    }
    *flag = (cnt >= 8) ? 1 : 0;  // 1 = fp32, 0 = bf16
  }
}

// ---- Phase A: bin edge entries by 512-row bucket into csr_tmp ----
__global__ __launch_bounds__(256, 4) void k_fill_binned(
    const int2* __restrict__ ea, const int2* __restrict__ eb,
    int* __restrict__ bkt_cnt, u32* __restrict__ csr_tmp, int E) {
  __shared__ u32 ein[2 * EPB];        // 16 KB
  __shared__ u16 ebkt[2 * EPB];       //  8 KB
  __shared__ int lcount[512];         // counts, then cursors
  __shared__ int lstart[513];
  __shared__ int gbase[512];
  __shared__ int ssc[256];

  const int tid = threadIdx.x;
  const int gofs = blockIdx.y ? N_ENT_C : 0;
  const int2* ed = blockIdx.y ? eb : ea;
  const int e0 = blockIdx.x * EPB;

  lcount[tid] = 0; lcount[tid + 256] = 0;
  __syncthreads();

  int2 ev[EPB / 256];
#pragma unroll
  for (int i = 0; i < EPB / 256; ++i) {
    int e = e0 + tid + i * 256;
    int2 v = (e < E) ? ed[e] : make_int2(0, 0);
    ev[i] = v;
    if (e < E) {
      atomicAdd(&lcount[(gofs + v.y) >> 9], 1);
      atomicAdd(&lcount[(gofs + v.x) >> 9], 1);
    }
  }
  __syncthreads();

  int a = lcount[2 * tid], b = lcount[2 * tid + 1];
  int ts = a + b;
  ssc[tid] = ts;
  __syncthreads();
  for (int off = 1; off < 256; off <<= 1) {
    int v = (tid >= off) ? ssc[tid - off] : 0;
    __syncthreads();
    ssc[tid] += v;
    __syncthreads();
  }
  int ex = ssc[tid] - ts;
  lstart[2 * tid] = ex;
  lstart[2 * tid + 1] = ex + a;
  if (tid == 255) lstart[512] = ssc[255];
  __syncthreads();

  {
    int b0 = 2 * tid, b1 = 2 * tid + 1;
    if (b0 < NBKT) { int c = lstart[b0 + 1] - lstart[b0]; gbase[b0] = c ? atomicAdd(&bkt_cnt[b0], c) : 0; }
    if (b1 < NBKT) { int c = lstart[b1 + 1] - lstart[b1]; gbase[b1] = c ? atomicAdd(&bkt_cnt[b1], c) : 0; }
    lcount[tid] = lstart[tid];
    lcount[tid + 256] = lstart[tid + 256];
  }
  __syncthreads();

#pragma unroll
  for (int i = 0; i < EPB / 256; ++i) {
    int e = e0 + tid + i * 256;
    if (e >= E) continue;
    int2 v = ev[i];
    int r1 = gofs + v.y;
    u32 w1 = (u32)v.x | ((u32)(r1 & 511) << 20);
    int bk1 = r1 >> 9;
    int p = atomicAdd(&lcount[bk1], 1);
    ein[p] = w1; ebkt[p] = (u16)bk1;
    int r2 = gofs + v.x;
    u32 w2 = (u32)v.y | ((u32)(r2 & 511) << 20);
    int bk2 = r2 >> 9;
    p = atomicAdd(&lcount[bk2], 1);
    ein[p] = w2; ebkt[p] = (u16)bk2;
  }
  __syncthreads();

  int tot = lstart[512];
  for (int j = tid; j < tot; j += 256) {
    int bk = ebkt[j];
    u32 off = (u32)(gbase[bk] + (j - lstart[bk]));
    if (off < BKT_CAP) csr_tmp[(size_t)bk * BKT_CAP + off] = ein[j];
  }
}

// ---- Phase B1: per-bucket row counts -> deg + rdeg (coalesced) ----
__global__ void k_deg(const u32* __restrict__ csr_tmp, const int* __restrict__ bkt_cnt,
                      int* __restrict__ deg, float* __restrict__ rdeg) {
  __shared__ int lcnt[512];
  int bk = blockIdx.x, tid = threadIdx.x;   // 512 threads
  lcnt[tid] = 0;
  __syncthreads();
  int cnt = min(bkt_cnt[bk], BKT_CAP);
  const u32* src = csr_tmp + (size_t)bk * BKT_CAP;
  for (int j = tid; j < cnt; j += 512)
    atomicAdd(&lcnt[(src[j] >> 20) & 511], 1);
  __syncthreads();
  int row = (bk << 9) + tid;
  if (row < N2_C) {
    int d = lcnt[tid];
    deg[row] = d;
    rdeg[row] = rsqrtf((float)(d + 1));
  }
}

// ---- 3-kernel exclusive scan of deg[n] -> row_start[n] ----
__global__ void k_scan1(const int* __restrict__ deg, int* __restrict__ row_start,
                        int* __restrict__ bsum, int n) {
  __shared__ int s[256];
  int b = blockIdx.x, tid = threadIdx.x;
  int i0 = b * 1024 + tid * 4;
  int d0 = (i0 + 0 < n) ? deg[i0 + 0] : 0;
  int d1 = (i0 + 1 < n) ? deg[i0 + 1] : 0;
  int d2 = (i0 + 2 < n) ? deg[i0 + 2] : 0;
  int d3 = (i0 + 3 < n) ? deg[i0 + 3] : 0;
  int tsum = d0 + d1 + d2 + d3;
  s[tid] = tsum;
  __syncthreads();
  for (int off = 1; off < 256; off <<= 1) {
    int v = (tid >= off) ? s[tid - off] : 0;
    __syncthreads();
    s[tid] += v;
    __syncthreads();
  }
  int toff = s[tid] - tsum;
  if (i0 + 0 < n) row_start[i0 + 0] = toff;
  if (i0 + 1 < n) row_start[i0 + 1] = toff + d0;
  if (i0 + 2 < n) row_start[i0 + 2] = toff + d0 + d1;
  if (i0 + 3 < n) row_start[i0 + 3] = toff + d0 + d1 + d2;
  if (tid == 255) bsum[b] = s[255];
}

__global__ void k_scan2(int* __restrict__ bsum, int nb) {
  __shared__ int s[256];
  int tid = threadIdx.x;
  int v = (tid < nb) ? bsum[tid] : 0;
  s[tid] = v;
  __syncthreads();
  for (int off = 1; off < 256; off <<= 1) {
    int u = (tid >= off) ? s[tid - off] : 0;
    __syncthreads();
    s[tid] += u;
    __syncthreads();
  }
  if (tid < nb) bsum[tid] = s[tid] - v;   // exclusive
}

__global__ void k_scan3(int* __restrict__ row_start, const int* __restrict__ bsum, int n) {
  int i = blockIdx.x * 256 + threadIdx.x;
  if (i < n) row_start[i] += bsum[i >> 10];
}

// ---- Phase B2: sort each bucket into final CSR {src, rdeg[src]} ----
__global__ void k_csr_sort(const u32* __restrict__ csr_tmp, const int* __restrict__ bkt_cnt,
                           const int* __restrict__ row_start, const float* __restrict__ rdeg,
                           int2* __restrict__ csr) {
  __shared__ int lcur[512];
  int bk = blockIdx.x, tid = threadIdx.x;   // 512 threads
  int rb0 = bk << 9;
  int base = row_start[rb0];
  {
    int row = rb0 + tid;
    lcur[tid] = (row < N2_C) ? row_start[row] - base : 0;
  }
  __syncthreads();
  int cnt = min(bkt_cnt[bk], BKT_CAP);
  const u32* srcp = csr_tmp + (size_t)bk * BKT_CAP;
  for (int j = tid; j < cnt; j += 512) {
    u32 w = srcp[j];
    int dl = (w >> 20) & 511;
    int s = w & 0x1FFFF;
    int pos = atomicAdd(&lcur[dl], 1);
    float r = rdeg[((rb0 + dl) >= N_ENT_C ? N_ENT_C : 0) + s];
    csr[base + pos] = make_int2(s, __float_as_int(r));
  }
}

// emb (fp32 or bf16 per flag) -> packed bf16 x. 16 B out per thread.
__global__ void k_cvt_bf16(const void* __restrict__ s0, const void* __restrict__ s1,
                           u32* __restrict__ d0, u32* __restrict__ d1,
                           const int* __restrict__ flag, int n4) {
  int i = blockIdx.x * 256 + threadIdx.x;
  if (i >= n4) return;
  const void* src = blockIdx.y ? s1 : s0;
  u32* dst = blockIdx.y ? d1 : d0;
  uint4 o;
  if (*flag) {
    const float4* sf = (const float4*)src;
    float4 va = sf[2 * i], vb = sf[2 * i + 1];
    o.x = (u32)f2bf(va.x) | ((u32)f2bf(va.y) << 16);
    o.y = (u32)f2bf(va.z) | ((u32)f2bf(va.w) << 16);
    o.z = (u32)f2bf(vb.x) | ((u32)f2bf(vb.y) << 16);
    o.w = (u32)f2bf(vb.z) | ((u32)f2bf(vb.w) << 16);
  } else {
    o = ((const uint4*)src)[i];
  }
  ((uint4*)dst)[i] = o;
}

// 2-entry / 1-entry gather steps
#define G2(cp, t, a0, a1) { \
  int2 e0 = cp[t], e1 = cp[(t) + 1]; \
  u32 v0 = xin[((u32)e0.x << 6) | lane]; \
  u32 v1 = xin[((u32)e1.x << 6) | lane]; \
  float r0 = __int_as_float(e0.y), r1 = __int_as_float(e1.y); \
  a0 += r0 * bflo(v0) + r1 * bflo(v1); \
  a1 += r0 * bfhi(v0) + r1 * bfhi(v1); }
#define G1(cp, t, a0, a1) { \
  int2 e0 = cp[t]; \
  u32 v0 = xin[((u32)e0.x << 6) | lane]; \
  float r0 = __int_as_float(e0.y); \
  a0 += r0 * bflo(v0); a1 += r0 * bfhi(v0); }

// Fused GCN layer. 512 threads (8 waves), 64 rows/block. LDS 48 KB -> 3 blk/CU
// = 24 waves/CU. Gather pairs two rows per wave (2+2 interleaved loads).
// If fout != null: write fp32 directly to out_ent (final layer).
// (Round-4-proven configuration — measured 553 us total.)
__global__ __launch_bounds__(512, 6) void k_fused(
    const int* __restrict__ row_start, const int* __restrict__ deg,
    const int2* __restrict__ csr2, const u32* __restrict__ xin0,
    const u32* __restrict__ xin1, const float* __restrict__ rdeg,
    const void* __restrict__ W, const int* __restrict__ flag,
    u32* __restrict__ xout0, u32* __restrict__ xout1,
    float* __restrict__ fout0, float* __restrict__ fout1) {
  __shared__ __align__(16) u16 smem[128 * 128 + 64 * 128];  // 49152 B
  u16* sWt = smem;               // 128x128 bf16 W^T, swizzled
  u16* sA  = smem + 128 * 128;   // 64x128 bf16 A-tile, swizzled

  const int tid = threadIdx.x;
  const int row0 = blockIdx.x * 64;
  const int gofs = blockIdx.y * N_ENT_C;
  const u32* __restrict__ xin  = blockIdx.y ? xin1  : xin0;
  u32* __restrict__ xout       = blockIdx.y ? xout1 : xout0;
  float* __restrict__ fout     = blockIdx.y ? fout1 : fout0;
  const int* rsb = row_start + gofs;
  const int* dgb = deg + gofs;
  const float* rdb = rdeg + gofs;
  const int isf32 = *flag;

  // ---- stage W^T (bf16), swizzled: u32 word (n, k2) at n*64 + (k2 ^ ((n&7)<<2))
  {
    u32* sW32 = (u32*)sWt;
    const float* Wf = (const float*)W;
    const u16*   Wu = (const u16*)W;
    for (int i = tid; i < 64 * 128; i += 512) {
      int k2 = i >> 7;        // pair of k: 2*k2, 2*k2+1
      int n  = i & 127;
      u16 lo, hi;
      if (isf32) { lo = f2bf(Wf[(2 * k2) * 128 + n]); hi = f2bf(Wf[(2 * k2 + 1) * 128 + n]); }
      else       { lo = Wu[(2 * k2) * 128 + n];       hi = Wu[(2 * k2 + 1) * 128 + n]; }
      sW32[n * 64 + (k2 ^ ((n & 7) << 2))] = (u32)lo | ((u32)hi << 16);
    }
  }

  // ---- gather: wave w owns rows [w*8, w*8+8), processed as 4 pairs ----
  const int wave = tid >> 6, lane = tid & 63;
  for (int pq = 0; pq < 4; ++pq) {
    const int rlA = wave * 8 + 2 * pq, rlB = rlA + 1;
    const int rowA = row0 + rlA, rowB = row0 + rlB;
    const bool vA = rowA < N_ENT_C, vB = rowB < N_ENT_C;
    int rsA = vA ? rsb[rowA] : 0, deA = vA ? dgb[rowA] : 0;
    int rsB = vB ? rsb[rowB] : 0, deB = vB ? dgb[rowB] : 0;
    rsA = __builtin_amdgcn_readfirstlane(rsA); deA = __builtin_amdgcn_readfirstlane(deA);
    rsB = __builtin_amdgcn_readfirstlane(rsB); deB = __builtin_amdgcn_readfirstlane(deB);
    const float rdA = vA ? rdb[rowA] : 0.f, rdB = vB ? rdb[rowB] : 0.f;
    const u32 vsA = vA ? xin[((u32)rowA << 6) | lane] : 0u;
    const u32 vsB = vB ? xin[((u32)rowB << 6) | lane] : 0u;
    const int2* cA = csr2 + rsA;
    const int2* cB = csr2 + rsB;
    float a0A = 0.f, a1A = 0.f, a0B = 0.f, a1B = 0.f;
    int tA = 0, tB = 0;
    // joint phase: two independent chains, 4 xin loads in flight
    while (tA + 1 < deA && tB + 1 < deB) {
      int2 eA0 = cA[tA], eA1 = cA[tA + 1];
      int2 eB0 = cB[tB], eB1 = cB[tB + 1];
      u32 uA0 = xin[((u32)eA0.x << 6) | lane];
      u32 uA1 = xin[((u32)eA1.x << 6) | lane];
      u32 uB0 = xin[((u32)eB0.x << 6) | lane];
      u32 uB1 = xin[((u32)eB1.x << 6) | lane];
      float rA0 = __int_as_float(eA0.y), rA1 = __int_as_float(eA1.y);
      float rB0 = __int_as_float(eB0.y), rB1 = __int_as_float(eB1.y);
      a0A += rA0 * bflo(uA0) + rA1 * bflo(uA1);
      a1A += rA0 * bfhi(uA0) + rA1 * bfhi(uA1);
      a0B += rB0 * bflo(uB0) + rB1 * bflo(uB1);
      a1B += rB0 * bfhi(uB0) + rB1 * bfhi(uB1);
      tA += 2; tB += 2;
    }
    // drains (one of the two rows typically has entries left)
    for (; tA + 3 < deA; tA += 4) { G2(cA, tA, a0A, a1A); G2(cA, tA + 2, a0A, a1A); }
    if (tA + 1 < deA) { G2(cA, tA, a0A, a1A); tA += 2; }
    if (tA < deA) G1(cA, tA, a0A, a1A);
    for (; tB + 3 < deB; tB += 4) { G2(cB, tB, a0B, a1B); G2(cB, tB + 2, a0B, a1B); }
    if (tB + 1 < deB) { G2(cB, tB, a0B, a1B); tB += 2; }
    if (tB < deB) G1(cB, tB, a0B, a1B);

    a0A = rdA * a0A + rdA * rdA * bflo(vsA);
    a1A = rdA * a1A + rdA * rdA * bfhi(vsA);
    a0B = rdB * a0B + rdB * rdB * bflo(vsB);
    a1B = rdB * a1B + rdB * rdB * bfhi(vsB);
    ((u32*)sA)[rlA * 64 + (lane ^ ((rlA & 7) << 2))] = (u32)f2bf(a0A) | ((u32)f2bf(a1A) << 16);
    ((u32*)sA)[rlB * 64 + (lane ^ ((rlB & 7) << 2))] = (u32)f2bf(a0B) | ((u32)f2bf(a1B) << 16);
  }
  __syncthreads();

  // ---- MFMA: 8 waves, wave -> 16 rows x 64 cols ----
  const int rows_h = (wave >> 1) * 16;   // 0 | 16 | 32 | 48
  const int col_q  = (wave & 1) * 64;    // 0 | 64
  const int m = lane & 15, q = lane >> 4;
  f32x4 acc[4];
  for (int ct = 0; ct < 4; ++ct) acc[ct] = (f32x4){0.f, 0.f, 0.f, 0.f};
#pragma unroll
  for (int kt = 0; kt < 4; ++kt) {
    int k0 = kt * 32 + q * 8;
    int ks = k0 ^ ((m & 7) << 3);        // same swizzle for A row and W^T rows
    bf16x8 a = *(const bf16x8*)&sA[(rows_h + m) * 128 + ks];
#pragma unroll
    for (int ct = 0; ct < 4; ++ct) {
      bf16x8 b = *(const bf16x8*)&sWt[(col_q + ct * 16 + m) * 128 + ks];
      acc[ct] = __builtin_amdgcn_mfma_f32_16x16x32_bf16(a, b, acc[ct], 0, 0, 0);
    }
  }
  __syncthreads();   // all waves done reading sWt/sA before C overwrites smem

  // ---- C (fp32) into LDS for coalesced epilogue ----
  float* sC = (float*)smem;              // 64 x 132 fp32 = 33792 B (fits 48 KB)
#pragma unroll
  for (int ct = 0; ct < 4; ++ct)
#pragma unroll
    for (int r = 0; r < 4; ++r)
      sC[(rows_h + q * 4 + r) * 132 + (col_q + ct * 16 + m)] = acc[ct][r];
  __syncthreads();

  // ---- epilogue: +residual, relu; fp32 direct out (final) or bf16 pack ----
  {
    int rowl = tid >> 3;                 // 0..63
    int c0 = (tid & 7) * 16;
    int row = row0 + rowl;
    if (row < N_ENT_C) {
      size_t goff = (size_t)row * 64 + (c0 >> 1);  // in u32 units
      const u32* resp = xin + goff;
      if (fout) {
        float* op = fout + (size_t)row * 128 + c0;
#pragma unroll
        for (int u2 = 0; u2 < 4; ++u2) {
          u32 rv0 = resp[2 * u2], rv1 = resp[2 * u2 + 1];
          f32x4 f;
          f[0] = fmaxf(sC[rowl * 132 + c0 + 4 * u2    ] + bflo(rv0), 0.f);
          f[1] = fmaxf(sC[rowl * 132 + c0 + 4 * u2 + 1] + bfhi(rv0), 0.f);
          f[2] = fmaxf(sC[rowl * 132 + c0 + 4 * u2 + 2] + bflo(rv1), 0.f);
          f[3] = fmaxf(sC[rowl * 132 + c0 + 4 * u2 + 3] + bfhi(rv1), 0.f);
          __builtin_nontemporal_store(f, (f32x4*)(op + 4 * u2));
        }
      } else {
        u32 ov[8];
#pragma unroll
        for (int u = 0; u < 8; ++u) {
          u32 rv = resp[u];
          float lo = fmaxf(sC[rowl * 132 + c0 + 2 * u]     + bflo(rv), 0.f);
          float hi = fmaxf(sC[rowl * 132 + c0 + 2 * u + 1] + bfhi(rv), 0.f);
          ov[u] = (u32)f2bf(lo) | ((u32)f2bf(hi) << 16);
        }
        uint4* op = (uint4*)(xout + goff);
        op[0] = make_uint4(ov[0], ov[1], ov[2], ov[3]);
        op[1] = make_uint4(ov[4], ov[5], ov[6], ov[7]);
      }
    }
  }
}

// Seed outputs: copy fp32 rows from out_ent (already final fp32).
__global__ void k_out_seed(const float4* __restrict__ ea, const float4* __restrict__ eb,
                           const int* __restrict__ sa, const int* __restrict__ sb,
                           float4* __restrict__ oa, float4* __restrict__ ob, int total4) {
  int t = blockIdx.x * 256 + threadIdx.x;
  if (t >= total4) return;
  const float4* e = blockIdx.y ? eb : ea;
  const int* seeds = blockIdx.y ? sb : sa;
  float4* o = blockIdx.y ? ob : oa;
  int s = t >> 5, w = t & 31;            // 32 float4 per row
  o[t] = e[((size_t)seeds[s] << 5) | w];
}

extern "C" void kernel_launch(void* const* d_in, const int* in_sizes, int n_in,
                              void* d_out, int out_size, void* d_ws, size_t ws_size,
                              hipStream_t stream) {
  const int*  sr_seeds = (const int*)d_in[0];
  const int*  tg_seeds = (const int*)d_in[1];
  // d_in[2], d_in[3]: triples_* — unused by the reference.
  const void* emb_sr   = d_in[4];
  const void* emb_tg   = d_in[5];
  const int*  edges_sr = (const int*)d_in[6];
  const int*  edges_tg = (const int*)d_in[7];
  const void* W1       = d_in[8];
  const void* W2       = d_in[9];
  float* out = (float*)d_out;

  const int nd = N_ENT_C * DIM_C;  // 12,800,000

  // ws layout (~95.2 MB of >=102.8 MB proven):
  u16* x_A       = (u16*)d_ws;                    // 25.6 MB (cvt out sr, L1 in)
  u16* x_B       = x_A + (size_t)nd;              // 25.6 MB (cvt out tg, L1 in)
  float* ws_rdeg = (float*)(x_B + (size_t)nd);    // 800 KB (2N)
  int* ws_flag   = (int*)(ws_rdeg + N2_C);        // 256 B
  int* deg       = ws_flag + 64;                  // 800 KB (2N)
  int* row_start = deg + N2_C;                    // 800 KB (2N)
  int* bsum      = row_start + N2_C;              // 4 KB
  int* bkt_cnt   = bsum + 1024;                   // 2 KB
  int2* csr      = (int2*)(bkt_cnt + 512);        // 16 MB  (2M entries {src, rdeg})
  u32* csr_tmp   = (u32*)(csr + (size_t)4 * N_EDGE_C);  // 12.8 MB, dead after sort
  u16* x_C       = (u16*)csr_tmp;                 // 25.6 MB overlay (L1-sr out, L2 in)

  float* out_seed_sr = out;
  float* out_seed_tg = out + (size_t)N_SEED_C * DIM_C;
  float* out_ent_sr  = out + (size_t)2 * N_SEED_C * DIM_C;
  float* out_ent_tg  = out_ent_sr + (size_t)nd;

  // x_D (L1 out tg) lives in out_ent_sr region; consumed by L2-tg BEFORE
  // L2-sr overwrites that region with fp32 (in-order stream).
  u16* x_D = (u16*)out_ent_sr;

  k_detect<<<1, 256, 0, stream>>>((const u32*)emb_sr, ws_flag, bkt_cnt);

  // ---- binned CSR build (both graphs concatenated) ----
  dim3 agrid((N_EDGE_C + EPB - 1) / EPB, 2);      // 245 x 2
  k_fill_binned<<<agrid, 256, 0, stream>>>((const int2*)edges_sr, (const int2*)edges_tg,
                                           bkt_cnt, csr_tmp, N_EDGE_C);
  k_deg<<<NBKT, 512, 0, stream>>>(csr_tmp, bkt_cnt, deg, ws_rdeg);

  const int NB_SCAN = (N2_C + 1023) / 1024;       // 196
  k_scan1<<<NB_SCAN, 256, 0, stream>>>(deg, row_start, bsum, N2_C);
  k_scan2<<<1, 256, 0, stream>>>(bsum, NB_SCAN);
  k_scan3<<<(N2_C + 255) / 256, 256, 0, stream>>>(row_start, bsum, N2_C);

  k_csr_sort<<<NBKT, 512, 0, stream>>>(csr_tmp, bkt_cnt, row_start, ws_rdeg, csr);

  // ---- embeddings -> bf16 (both graphs, one dispatch, 16B/thread) ----
  dim3 cgrid((nd / 8 + 255) / 256, 2);
  k_cvt_bf16<<<cgrid, 256, 0, stream>>>(emb_sr, emb_tg, (u32*)x_A, (u32*)x_B, ws_flag, nd / 8);

  const int NBF = (N_ENT_C + 63) / 64;            // 1563

  // ---- L1: A,B -> C,D (bf16), both graphs in one dispatch ----
  dim3 f2grid(NBF, 2);
  k_fused<<<f2grid, 512, 0, stream>>>(row_start, deg, csr, (const u32*)x_A, (const u32*)x_B,
                                      ws_rdeg, W1, ws_flag, (u32*)x_C, (u32*)x_D,
                                      nullptr, nullptr);

  // ---- L2-tg first (reads x_D in out_ent_sr region), writes fp32 out_ent_tg ----
  k_fused<<<dim3(NBF, 1), 512, 0, stream>>>(row_start + N_ENT_C, deg + N_ENT_C, csr,
                                            (const u32*)x_D, nullptr, ws_rdeg + N_ENT_C,
                                            W2, ws_flag, nullptr, nullptr,
                                            out_ent_tg, nullptr);
  // ---- L2-sr: reads x_C (ws), writes fp32 out_ent_sr (clobbers dead x_D) ----
  k_fused<<<dim3(NBF, 1), 512, 0, stream>>>(row_start, deg, csr,
                                            (const u32*)x_C, nullptr, ws_rdeg,
                                            W2, ws_flag, nullptr, nullptr,
                                            out_ent_sr, nullptr);

  // ---- seed outputs: fp32 row copies from out_ent ----
  dim3 sgrid((N_SEED_C * 32 + 255) / 256, 2);
  k_out_seed<<<sgrid, 256, 0, stream>>>((const float4*)out_ent_sr, (const float4*)out_ent_tg,
                                        sr_seeds, tg_seeds,
                                        (float4*)out_seed_sr, (float4*)out_seed_tg,
                                        N_SEED_C * 32);
}

// Round 8
// 523.877 us; speedup vs baseline: 1.0569x; 1.0569x over previous
//
#include <hip/hip_runtime.h>
#include <hip/hip_bf16.h>

#define N_ENT_C   100000
#define N_EDGE_C  500000
#define N_SEED_C  10000
#define DIM_C     128

#define N2_C      (2 * N_ENT_C)     // concat rows (both graphs)
#define NBKT      391               // ceil(N2 / 512)
#define BKT_CAP   8192              // entries per bucket (mean 5120, 43 sigma safe)
#define EPB       2048              // edges per block in phase A (490 blocks)

typedef unsigned int   u32;
typedef unsigned short u16;
typedef __attribute__((ext_vector_type(8))) short bf16x8;
typedef __attribute__((ext_vector_type(4))) float f32x4;

__device__ __forceinline__ float bflo(u32 v) { return __uint_as_float(v << 16); }
__device__ __forceinline__ float bfhi(u32 v) { return __uint_as_float(v & 0xFFFF0000u); }
__device__ __forceinline__ u16 f2bf(float f) {       // RNE
  u32 u = __float_as_uint(f);
  u += 0x7FFFu + ((u >> 16) & 1u);
  return (u16)(u >> 16);
}

// Detect fp32 vs packed bf16 input; also zero the bucket counters.
__global__ void k_detect(const u32* __restrict__ words, int* __restrict__ flag,
                         int* __restrict__ bkt_cnt) {
  int tid = threadIdx.x;
  bkt_cnt[tid] = 0;
  bkt_cnt[tid + 256] = 0;
  if (tid == 0) {
    int cnt = 0;
    for (int i = 0; i < 64; ++i) {
      u32 e = (words[i] >> 7) & 0xFF;
      cnt += (e < 96) ? 1 : 0;
    }
    *flag = (cnt >= 8) ? 1 : 0;  // 1 = fp32, 0 = bf16
  }
}

// ---- Phase A: bin edge entries by 512-row bucket into csr_tmp ----
__global__ __launch_bounds__(256, 4) void k_fill_binned(
    const int2* __restrict__ ea, const int2* __restrict__ eb,
    int* __restrict__ bkt_cnt, u32* __restrict__ csr_tmp, int E) {
  __shared__ u32 ein[2 * EPB];        // 16 KB
  __shared__ u16 ebkt[2 * EPB];       //  8 KB
  __shared__ int lcount[512];         // counts, then cursors
  __shared__ int lstart[513];
  __shared__ int gbase[512];
  __shared__ int ssc[256];

  const int tid = threadIdx.x;
  const int gofs = blockIdx.y ? N_ENT_C : 0;
  const int2* ed = blockIdx.y ? eb : ea;
  const int e0 = blockIdx.x * EPB;

  lcount[tid] = 0; lcount[tid + 256] = 0;
  __syncthreads();

  int2 ev[EPB / 256];
#pragma unroll
  for (int i = 0; i < EPB / 256; ++i) {
    int e = e0 + tid + i * 256;
    int2 v = (e < E) ? ed[e] : make_int2(0, 0);
    ev[i] = v;
    if (e < E) {
      atomicAdd(&lcount[(gofs + v.y) >> 9], 1);
      atomicAdd(&lcount[(gofs + v.x) >> 9], 1);
    }
  }
  __syncthreads();

  int a = lcount[2 * tid], b = lcount[2 * tid + 1];
  int ts = a + b;
  ssc[tid] = ts;
  __syncthreads();
  for (int off = 1; off < 256; off <<= 1) {
    int v = (tid >= off) ? ssc[tid - off] : 0;
    __syncthreads();
    ssc[tid] += v;
    __syncthreads();
  }
  int ex = ssc[tid] - ts;
  lstart[2 * tid] = ex;
  lstart[2 * tid + 1] = ex + a;
  if (tid == 255) lstart[512] = ssc[255];
  __syncthreads();

  {
    int b0 = 2 * tid, b1 = 2 * tid + 1;
    if (b0 < NBKT) { int c = lstart[b0 + 1] - lstart[b0]; gbase[b0] = c ? atomicAdd(&bkt_cnt[b0], c) : 0; }
    if (b1 < NBKT) { int c = lstart[b1 + 1] - lstart[b1]; gbase[b1] = c ? atomicAdd(&bkt_cnt[b1], c) : 0; }
    lcount[tid] = lstart[tid];
    lcount[tid + 256] = lstart[tid + 256];
  }
  __syncthreads();

#pragma unroll
  for (int i = 0; i < EPB / 256; ++i) {
    int e = e0 + tid + i * 256;
    if (e >= E) continue;
    int2 v = ev[i];
    int r1 = gofs + v.y;
    u32 w1 = (u32)v.x | ((u32)(r1 & 511) << 20);
    int bk1 = r1 >> 9;
    int p = atomicAdd(&lcount[bk1], 1);
    ein[p] = w1; ebkt[p] = (u16)bk1;
    int r2 = gofs + v.x;
    u32 w2 = (u32)v.y | ((u32)(r2 & 511) << 20);
    int bk2 = r2 >> 9;
    p = atomicAdd(&lcount[bk2], 1);
    ein[p] = w2; ebkt[p] = (u16)bk2;
  }
  __syncthreads();

  int tot = lstart[512];
  for (int j = tid; j < tot; j += 256) {
    int bk = ebkt[j];
    u32 off = (u32)(gbase[bk] + (j - lstart[bk]));
    if (off < BKT_CAP) csr_tmp[(size_t)bk * BKT_CAP + off] = ein[j];
  }
}

// ---- Phase B1: per-bucket row counts -> deg + rdeg (coalesced) ----
__global__ void k_deg(const u32* __restrict__ csr_tmp, const int* __restrict__ bkt_cnt,
                      int* __restrict__ deg, float* __restrict__ rdeg) {
  __shared__ int lcnt[512];
  int bk = blockIdx.x, tid = threadIdx.x;   // 512 threads
  lcnt[tid] = 0;
  __syncthreads();
  int cnt = min(bkt_cnt[bk], BKT_CAP);
  const u32* src = csr_tmp + (size_t)bk * BKT_CAP;
  for (int j = tid; j < cnt; j += 512)
    atomicAdd(&lcnt[(src[j] >> 20) & 511], 1);
  __syncthreads();
  int row = (bk << 9) + tid;
  if (row < N2_C) {
    int d = lcnt[tid];
    deg[row] = d;
    rdeg[row] = rsqrtf((float)(d + 1));
  }
}

// ---- 3-kernel exclusive scan of deg[n] -> row_start[n] ----
__global__ void k_scan1(const int* __restrict__ deg, int* __restrict__ row_start,
                        int* __restrict__ bsum, int n) {
  __shared__ int s[256];
  int b = blockIdx.x, tid = threadIdx.x;
  int i0 = b * 1024 + tid * 4;
  int d0 = (i0 + 0 < n) ? deg[i0 + 0] : 0;
  int d1 = (i0 + 1 < n) ? deg[i0 + 1] : 0;
  int d2 = (i0 + 2 < n) ? deg[i0 + 2] : 0;
  int d3 = (i0 + 3 < n) ? deg[i0 + 3] : 0;
  int tsum = d0 + d1 + d2 + d3;
  s[tid] = tsum;
  __syncthreads();
  for (int off = 1; off < 256; off <<= 1) {
    int v = (tid >= off) ? s[tid - off] : 0;
    __syncthreads();
    s[tid] += v;
    __syncthreads();
  }
  int toff = s[tid] - tsum;
  if (i0 + 0 < n) row_start[i0 + 0] = toff;
  if (i0 + 1 < n) row_start[i0 + 1] = toff + d0;
  if (i0 + 2 < n) row_start[i0 + 2] = toff + d0 + d1;
  if (i0 + 3 < n) row_start[i0 + 3] = toff + d0 + d1 + d2;
  if (tid == 255) bsum[b] = s[255];
}

__global__ void k_scan2(int* __restrict__ bsum, int nb) {
  __shared__ int s[256];
  int tid = threadIdx.x;
  int v = (tid < nb) ? bsum[tid] : 0;
  s[tid] = v;
  __syncthreads();
  for (int off = 1; off < 256; off <<= 1) {
    int u = (tid >= off) ? s[tid - off] : 0;
    __syncthreads();
    s[tid] += u;
    __syncthreads();
  }
  if (tid < nb) bsum[tid] = s[tid] - v;   // exclusive
}

__global__ void k_scan3(int* __restrict__ row_start, const int* __restrict__ bsum, int n) {
  int i = blockIdx.x * 256 + threadIdx.x;
  if (i < n) row_start[i] += bsum[i >> 10];
}

// ---- Phase B2: sort each bucket into final CSR {src, rdeg[src]} ----
__global__ void k_csr_sort(const u32* __restrict__ csr_tmp, const int* __restrict__ bkt_cnt,
                           const int* __restrict__ row_start, const float* __restrict__ rdeg,
                           int2* __restrict__ csr) {
  __shared__ int lcur[512];
  int bk = blockIdx.x, tid = threadIdx.x;   // 512 threads
  int rb0 = bk << 9;
  int base = row_start[rb0];
  {
    int row = rb0 + tid;
    lcur[tid] = (row < N2_C) ? row_start[row] - base : 0;
  }
  __syncthreads();
  int cnt = min(bkt_cnt[bk], BKT_CAP);
  const u32* srcp = csr_tmp + (size_t)bk * BKT_CAP;
  for (int j = tid; j < cnt; j += 512) {
    u32 w = srcp[j];
    int dl = (w >> 20) & 511;
    int s = w & 0x1FFFF;
    int pos = atomicAdd(&lcur[dl], 1);
    float r = rdeg[((rb0 + dl) >= N_ENT_C ? N_ENT_C : 0) + s];
    csr[base + pos] = make_int2(s, __float_as_int(r));
  }
}

// emb (fp32 or bf16 per flag) -> packed bf16 x. 16 B out per thread.
__global__ void k_cvt_bf16(const void* __restrict__ s0, const void* __restrict__ s1,
                           u32* __restrict__ d0, u32* __restrict__ d1,
                           const int* __restrict__ flag, int n4) {
  int i = blockIdx.x * 256 + threadIdx.x;
  if (i >= n4) return;
  const void* src = blockIdx.y ? s1 : s0;
  u32* dst = blockIdx.y ? d1 : d0;
  uint4 o;
  if (*flag) {
    const float4* sf = (const float4*)src;
    float4 va = sf[2 * i], vb = sf[2 * i + 1];
    o.x = (u32)f2bf(va.x) | ((u32)f2bf(va.y) << 16);
    o.y = (u32)f2bf(va.z) | ((u32)f2bf(va.w) << 16);
    o.z = (u32)f2bf(vb.x) | ((u32)f2bf(vb.y) << 16);
    o.w = (u32)f2bf(vb.z) | ((u32)f2bf(vb.w) << 16);
  } else {
    o = ((const uint4*)src)[i];
  }
  ((uint4*)dst)[i] = o;
}

// 2-entry / 1-entry gather steps
#define G2(cp, t, a0, a1) { \
  int2 e0 = cp[t], e1 = cp[(t) + 1]; \
  u32 v0 = xin[((u32)e0.x << 6) | lane]; \
  u32 v1 = xin[((u32)e1.x << 6) | lane]; \
  float r0 = __int_as_float(e0.y), r1 = __int_as_float(e1.y); \
  a0 += r0 * bflo(v0) + r1 * bflo(v1); \
  a1 += r0 * bfhi(v0) + r1 * bfhi(v1); }
#define G1(cp, t, a0, a1) { \
  int2 e0 = cp[t]; \
  u32 v0 = xin[((u32)e0.x << 6) | lane]; \
  float r0 = __int_as_float(e0.y); \
  a0 += r0 * bflo(v0); a1 += r0 * bfhi(v0); }

// Fused GCN layer. 512 threads (8 waves), 32 rows/block. LDS = 40960 B exactly
// -> 4 blocks/CU x 8 waves = 32 waves/CU (architectural max; was 24).
// Gather pairs two rows per wave (unchanged, measured-good). MFMA: 8 waves,
// each 16 rows x 32 cols. If fout != null: write fp32 directly to out_ent.
__global__ __launch_bounds__(512, 8) void k_fused(
    const int* __restrict__ row_start, const int* __restrict__ deg,
    const int2* __restrict__ csr2, const u32* __restrict__ xin0,
    const u32* __restrict__ xin1, const float* __restrict__ rdeg,
    const void* __restrict__ W, const int* __restrict__ flag,
    u32* __restrict__ xout0, u32* __restrict__ xout1,
    float* __restrict__ fout0, float* __restrict__ fout1) {
  __shared__ __align__(16) u16 smem[128 * 128 + 32 * 128];  // 40960 B
  u16* sWt = smem;               // 128x128 bf16 W^T, swizzled (32 KB)
  u16* sA  = smem + 128 * 128;   // 32x128 bf16 A-tile, swizzled (8 KB)

  const int tid = threadIdx.x;
  const int row0 = blockIdx.x * 32;
  const int gofs = blockIdx.y * N_ENT_C;
  const u32* __restrict__ xin  = blockIdx.y ? xin1  : xin0;
  u32* __restrict__ xout       = blockIdx.y ? xout1 : xout0;
  float* __restrict__ fout     = blockIdx.y ? fout1 : fout0;
  const int* rsb = row_start + gofs;
  const int* dgb = deg + gofs;
  const float* rdb = rdeg + gofs;
  const int isf32 = *flag;

  // ---- stage W^T (bf16), swizzled: u32 word (n, k2) at n*64 + (k2 ^ ((n&7)<<2))
  {
    u32* sW32 = (u32*)sWt;
    const float* Wf = (const float*)W;
    const u16*   Wu = (const u16*)W;
    for (int i = tid; i < 64 * 128; i += 512) {
      int k2 = i >> 7;        // pair of k: 2*k2, 2*k2+1
      int n  = i & 127;
      u16 lo, hi;
      if (isf32) { lo = f2bf(Wf[(2 * k2) * 128 + n]); hi = f2bf(Wf[(2 * k2 + 1) * 128 + n]); }
      else       { lo = Wu[(2 * k2) * 128 + n];       hi = Wu[(2 * k2 + 1) * 128 + n]; }
      sW32[n * 64 + (k2 ^ ((n & 7) << 2))] = (u32)lo | ((u32)hi << 16);
    }
  }

  // ---- gather: wave w owns rows [w*4, w*4+4), processed as 2 pairs ----
  const int wave = tid >> 6, lane = tid & 63;
  for (int pq = 0; pq < 2; ++pq) {
    const int rlA = wave * 4 + 2 * pq, rlB = rlA + 1;
    const int rowA = row0 + rlA, rowB = row0 + rlB;
    const bool vA = rowA < N_ENT_C, vB = rowB < N_ENT_C;
    int rsA = vA ? rsb[rowA] : 0, deA = vA ? dgb[rowA] : 0;
    int rsB = vB ? rsb[rowB] : 0, deB = vB ? dgb[rowB] : 0;
    rsA = __builtin_amdgcn_readfirstlane(rsA); deA = __builtin_amdgcn_readfirstlane(deA);
    rsB = __builtin_amdgcn_readfirstlane(rsB); deB = __builtin_amdgcn_readfirstlane(deB);
    const float rdA = vA ? rdb[rowA] : 0.f, rdB = vB ? rdb[rowB] : 0.f;
    const u32 vsA = vA ? xin[((u32)rowA << 6) | lane] : 0u;
    const u32 vsB = vB ? xin[((u32)rowB << 6) | lane] : 0u;
    const int2* cA = csr2 + rsA;
    const int2* cB = csr2 + rsB;
    float a0A = 0.f, a1A = 0.f, a0B = 0.f, a1B = 0.f;
    int tA = 0, tB = 0;
    // joint phase: two independent chains, 4 xin loads in flight
    while (tA + 1 < deA && tB + 1 < deB) {
      int2 eA0 = cA[tA], eA1 = cA[tA + 1];
      int2 eB0 = cB[tB], eB1 = cB[tB + 1];
      u32 uA0 = xin[((u32)eA0.x << 6) | lane];
      u32 uA1 = xin[((u32)eA1.x << 6) | lane];
      u32 uB0 = xin[((u32)eB0.x << 6) | lane];
      u32 uB1 = xin[((u32)eB1.x << 6) | lane];
      float rA0 = __int_as_float(eA0.y), rA1 = __int_as_float(eA1.y);
      float rB0 = __int_as_float(eB0.y), rB1 = __int_as_float(eB1.y);
      a0A += rA0 * bflo(uA0) + rA1 * bflo(uA1);
      a1A += rA0 * bfhi(uA0) + rA1 * bfhi(uA1);
      a0B += rB0 * bflo(uB0) + rB1 * bflo(uB1);
      a1B += rB0 * bfhi(uB0) + rB1 * bfhi(uB1);
      tA += 2; tB += 2;
    }
    // drains (one of the two rows typically has entries left)
    for (; tA + 3 < deA; tA += 4) { G2(cA, tA, a0A, a1A); G2(cA, tA + 2, a0A, a1A); }
    if (tA + 1 < deA) { G2(cA, tA, a0A, a1A); tA += 2; }
    if (tA < deA) G1(cA, tA, a0A, a1A);
    for (; tB + 3 < deB; tB += 4) { G2(cB, tB, a0B, a1B); G2(cB, tB + 2, a0B, a1B); }
    if (tB + 1 < deB) { G2(cB, tB, a0B, a1B); tB += 2; }
    if (tB < deB) G1(cB, tB, a0B, a1B);

    a0A = rdA * a0A + rdA * rdA * bflo(vsA);
    a1A = rdA * a1A + rdA * rdA * bfhi(vsA);
    a0B = rdB * a0B + rdB * rdB * bflo(vsB);
    a1B = rdB * a1B + rdB * rdB * bfhi(vsB);
    ((u32*)sA)[rlA * 64 + (lane ^ ((rlA & 7) << 2))] = (u32)f2bf(a0A) | ((u32)f2bf(a1A) << 16);
    ((u32*)sA)[rlB * 64 + (lane ^ ((rlB & 7) << 2))] = (u32)f2bf(a0B) | ((u32)f2bf(a1B) << 16);
  }
  __syncthreads();

  // ---- MFMA: 8 waves, wave -> 16 rows x 32 cols ----
  const int rows_h = (wave >> 2) * 16;   // 0 | 16
  const int col_q  = (wave & 3) * 32;    // 0 | 32 | 64 | 96
  const int m = lane & 15, q = lane >> 4;
  f32x4 acc[2];
  for (int ct = 0; ct < 2; ++ct) acc[ct] = (f32x4){0.f, 0.f, 0.f, 0.f};
#pragma unroll
  for (int kt = 0; kt < 4; ++kt) {
    int k0 = kt * 32 + q * 8;
    int ks = k0 ^ ((m & 7) << 3);        // same swizzle for A row and W^T rows
    bf16x8 a = *(const bf16x8*)&sA[(rows_h + m) * 128 + ks];
#pragma unroll
    for (int ct = 0; ct < 2; ++ct) {
      bf16x8 b = *(const bf16x8*)&sWt[(col_q + ct * 16 + m) * 128 + ks];
      acc[ct] = __builtin_amdgcn_mfma_f32_16x16x32_bf16(a, b, acc[ct], 0, 0, 0);
    }
  }
  __syncthreads();   // all waves done reading sWt/sA before C overwrites smem

  // ---- C (fp32) into LDS for coalesced epilogue ----
  float* sC = (float*)smem;              // 32 x 132 fp32 = 16896 B (fits 40 KB)
#pragma unroll
  for (int ct = 0; ct < 2; ++ct)
#pragma unroll
    for (int r = 0; r < 4; ++r)
      sC[(rows_h + q * 4 + r) * 132 + (col_q + ct * 16 + m)] = acc[ct][r];
  __syncthreads();

  // ---- epilogue: +residual, relu; fp32 direct out (final) or bf16 pack ----
  {
    int rowl = tid >> 4;                 // 0..31 (16 threads per row)
    int c0 = (tid & 15) * 8;             // 8 cols per thread
    int row = row0 + rowl;
    if (row < N_ENT_C) {
      size_t goff = (size_t)row * 64 + (c0 >> 1);  // in u32 units
      const u32* resp = xin + goff;
      if (fout) {
        float* op = fout + (size_t)row * 128 + c0;
#pragma unroll
        for (int u2 = 0; u2 < 2; ++u2) {
          u32 rv0 = resp[2 * u2], rv1 = resp[2 * u2 + 1];
          f32x4 f;
          f[0] = fmaxf(sC[rowl * 132 + c0 + 4 * u2    ] + bflo(rv0), 0.f);
          f[1] = fmaxf(sC[rowl * 132 + c0 + 4 * u2 + 1] + bfhi(rv0), 0.f);
          f[2] = fmaxf(sC[rowl * 132 + c0 + 4 * u2 + 2] + bflo(rv1), 0.f);
          f[3] = fmaxf(sC[rowl * 132 + c0 + 4 * u2 + 3] + bfhi(rv1), 0.f);
          __builtin_nontemporal_store(f, (f32x4*)(op + 4 * u2));
        }
      } else {
        u32 ov[4];
#pragma unroll
        for (int u = 0; u < 4; ++u) {
          u32 rv = resp[u];
          float lo = fmaxf(sC[rowl * 132 + c0 + 2 * u]     + bflo(rv), 0.f);
          float hi = fmaxf(sC[rowl * 132 + c0 + 2 * u + 1] + bfhi(rv), 0.f);
          ov[u] = (u32)f2bf(lo) | ((u32)f2bf(hi) << 16);
        }
        uint4* op = (uint4*)(xout + goff);
        op[0] = make_uint4(ov[0], ov[1], ov[2], ov[3]);
      }
    }
  }
}

// Seed outputs: copy fp32 rows from out_ent (already final fp32).
__global__ void k_out_seed(const float4* __restrict__ ea, const float4* __restrict__ eb,
                           const int* __restrict__ sa, const int* __restrict__ sb,
                           float4* __restrict__ oa, float4* __restrict__ ob, int total4) {
  int t = blockIdx.x * 256 + threadIdx.x;
  if (t >= total4) return;
  const float4* e = blockIdx.y ? eb : ea;
  const int* seeds = blockIdx.y ? sb : sa;
  float4* o = blockIdx.y ? ob : oa;
  int s = t >> 5, w = t & 31;            // 32 float4 per row
  o[t] = e[((size_t)seeds[s] << 5) | w];
}

extern "C" void kernel_launch(void* const* d_in, const int* in_sizes, int n_in,
                              void* d_out, int out_size, void* d_ws, size_t ws_size,
                              hipStream_t stream) {
  const int*  sr_seeds = (const int*)d_in[0];
  const int*  tg_seeds = (const int*)d_in[1];
  // d_in[2], d_in[3]: triples_* — unused by the reference.
  const void* emb_sr   = d_in[4];
  const void* emb_tg   = d_in[5];
  const int*  edges_sr = (const int*)d_in[6];
  const int*  edges_tg = (const int*)d_in[7];
  const void* W1       = d_in[8];
  const void* W2       = d_in[9];
  float* out = (float*)d_out;

  const int nd = N_ENT_C * DIM_C;  // 12,800,000

  // ws layout (~95.2 MB of >=102.8 MB proven):
  u16* x_A       = (u16*)d_ws;                    // 25.6 MB (cvt out sr, L1 in)
  u16* x_B       = x_A + (size_t)nd;              // 25.6 MB (cvt out tg, L1 in)
  float* ws_rdeg = (float*)(x_B + (size_t)nd);    // 800 KB (2N)
  int* ws_flag   = (int*)(ws_rdeg + N2_C);        // 256 B
  int* deg       = ws_flag + 64;                  // 800 KB (2N)
  int* row_start = deg + N2_C;                    // 800 KB (2N)
  int* bsum      = row_start + N2_C;              // 4 KB
  int* bkt_cnt   = bsum + 1024;                   // 2 KB
  int2* csr      = (int2*)(bkt_cnt + 512);        // 16 MB  (2M entries {src, rdeg})
  u32* csr_tmp   = (u32*)(csr + (size_t)4 * N_EDGE_C);  // 12.8 MB, dead after sort
  u16* x_C       = (u16*)csr_tmp;                 // 25.6 MB overlay (L1-sr out, L2 in)

  float* out_seed_sr = out;
  float* out_seed_tg = out + (size_t)N_SEED_C * DIM_C;
  float* out_ent_sr  = out + (size_t)2 * N_SEED_C * DIM_C;
  float* out_ent_tg  = out_ent_sr + (size_t)nd;

  // x_D (L1 out tg) lives in out_ent_sr region; consumed by L2-tg BEFORE
  // L2-sr overwrites that region with fp32 (in-order stream).
  u16* x_D = (u16*)out_ent_sr;

  k_detect<<<1, 256, 0, stream>>>((const u32*)emb_sr, ws_flag, bkt_cnt);

  // ---- binned CSR build (both graphs concatenated) ----
  dim3 agrid((N_EDGE_C + EPB - 1) / EPB, 2);      // 245 x 2
  k_fill_binned<<<agrid, 256, 0, stream>>>((const int2*)edges_sr, (const int2*)edges_tg,
                                           bkt_cnt, csr_tmp, N_EDGE_C);
  k_deg<<<NBKT, 512, 0, stream>>>(csr_tmp, bkt_cnt, deg, ws_rdeg);

  const int NB_SCAN = (N2_C + 1023) / 1024;       // 196
  k_scan1<<<NB_SCAN, 256, 0, stream>>>(deg, row_start, bsum, N2_C);
  k_scan2<<<1, 256, 0, stream>>>(bsum, NB_SCAN);
  k_scan3<<<(N2_C + 255) / 256, 256, 0, stream>>>(row_start, bsum, N2_C);

  k_csr_sort<<<NBKT, 512, 0, stream>>>(csr_tmp, bkt_cnt, row_start, ws_rdeg, csr);

  // ---- embeddings -> bf16 (both graphs, one dispatch, 16B/thread) ----
  dim3 cgrid((nd / 8 + 255) / 256, 2);
  k_cvt_bf16<<<cgrid, 256, 0, stream>>>(emb_sr, emb_tg, (u32*)x_A, (u32*)x_B, ws_flag, nd / 8);

  const int NBF = N_ENT_C / 32;                   // 3125

  // ---- L1: A,B -> C,D (bf16), both graphs in one dispatch ----
  dim3 f2grid(NBF, 2);
  k_fused<<<f2grid, 512, 0, stream>>>(row_start, deg, csr, (const u32*)x_A, (const u32*)x_B,
                                      ws_rdeg, W1, ws_flag, (u32*)x_C, (u32*)x_D,
                                      nullptr, nullptr);

  // ---- L2-tg first (reads x_D in out_ent_sr region), writes fp32 out_ent_tg ----
  k_fused<<<dim3(NBF, 1), 512, 0, stream>>>(row_start + N_ENT_C, deg + N_ENT_C, csr,
                                            (const u32*)x_D, nullptr, ws_rdeg + N_ENT_C,
                                            W2, ws_flag, nullptr, nullptr,
                                            out_ent_tg, nullptr);
  // ---- L2-sr: reads x_C (ws), writes fp32 out_ent_sr (clobbers dead x_D) ----
  k_fused<<<dim3(NBF, 1), 512, 0, stream>>>(row_start, deg, csr,
                                            (const u32*)x_C, nullptr, ws_rdeg,
                                            W2, ws_flag, nullptr, nullptr,
                                            out_ent_sr, nullptr);

  // ---- seed outputs: fp32 row copies from out_ent ----
  dim3 sgrid((N_SEED_C * 32 + 255) / 256, 2);
  k_out_seed<<<sgrid, 256, 0, stream>>>((const float4*)out_ent_sr, (const float4*)out_ent_tg,
                                        sr_seeds, tg_seeds,
                                        (float4*)out_seed_sr, (float4*)out_seed_tg,
                                        N_SEED_C * 32);
}

// Round 9
// 523.477 us; speedup vs baseline: 1.0577x; 1.0008x over previous
//
#include <hip/hip_runtime.h>
#include <hip/hip_bf16.h>

#define N_ENT_C   100000
#define N_EDGE_C  500000
#define N_SEED_C  10000
#define DIM_C     128

#define N2_C      (2 * N_ENT_C)     // concat rows (both graphs)
#define NBKT      391               // ceil(N2 / 512)
#define BKT_CAP   8192              // entries per bucket (mean 5120, 43 sigma safe)
#define EPB       2048              // edges per block in phase A

typedef unsigned int   u32;
typedef unsigned short u16;
typedef __attribute__((ext_vector_type(8))) short bf16x8;
typedef __attribute__((ext_vector_type(4))) float f32x4;

__device__ __forceinline__ float bflo(u32 v) { return __uint_as_float(v << 16); }
__device__ __forceinline__ float bfhi(u32 v) { return __uint_as_float(v & 0xFFFF0000u); }
__device__ __forceinline__ u16 f2bf(float f) {       // RNE
  u32 u = __float_as_uint(f);
  u += 0x7FFFu + ((u >> 16) & 1u);
  return (u16)(u >> 16);
}

// Detect fp32 vs packed bf16 input; also zero the bucket counters.
__global__ void k_detect(const u32* __restrict__ words, int* __restrict__ flag,
                         int* __restrict__ bkt_cnt) {
  int tid = threadIdx.x;
  bkt_cnt[tid] = 0;
  bkt_cnt[tid + 256] = 0;
  if (tid == 0) {
    int cnt = 0;
    for (int i = 0; i < 64; ++i) {
      u32 e = (words[i] >> 7) & 0xFF;
      cnt += (e < 96) ? 1 : 0;
    }
    *flag = (cnt >= 8) ? 1 : 0;  // 1 = fp32, 0 = bf16
  }
}

// ---- Phase A: bin edge entries by 512-row bucket into csr_tmp ----
// Entry: u32 = src | (dlocal << 20).
__global__ __launch_bounds__(256, 4) void k_fill_binned(
    const int2* __restrict__ ea, const int2* __restrict__ eb,
    int* __restrict__ bkt_cnt, u32* __restrict__ csr_tmp, int E) {
  __shared__ u32 ein[2 * EPB];        // 16 KB
  __shared__ u16 ebkt[2 * EPB];       //  8 KB
  __shared__ int lcount[512];         // counts, then cursors
  __shared__ int lstart[513];
  __shared__ int gbase[512];
  __shared__ int ssc[256];

  const int tid = threadIdx.x;
  const int gofs = blockIdx.y ? N_ENT_C : 0;
  const int2* ed = blockIdx.y ? eb : ea;
  const int e0 = blockIdx.x * EPB;

  lcount[tid] = 0; lcount[tid + 256] = 0;
  __syncthreads();

  int2 ev[EPB / 256];
#pragma unroll
  for (int i = 0; i < EPB / 256; ++i) {
    int e = e0 + tid + i * 256;
    int2 v = (e < E) ? ed[e] : make_int2(0, 0);
    ev[i] = v;
    if (e < E) {
      atomicAdd(&lcount[(gofs + v.y) >> 9], 1);
      atomicAdd(&lcount[(gofs + v.x) >> 9], 1);
    }
  }
  __syncthreads();

  int a = lcount[2 * tid], b = lcount[2 * tid + 1];
  int ts = a + b;
  ssc[tid] = ts;
  __syncthreads();
  for (int off = 1; off < 256; off <<= 1) {
    int v = (tid >= off) ? ssc[tid - off] : 0;
    __syncthreads();
    ssc[tid] += v;
    __syncthreads();
  }
  int ex = ssc[tid] - ts;
  lstart[2 * tid] = ex;
  lstart[2 * tid + 1] = ex + a;
  if (tid == 255) lstart[512] = ssc[255];
  __syncthreads();

  {
    int b0 = 2 * tid, b1 = 2 * tid + 1;
    if (b0 < NBKT) { int c = lstart[b0 + 1] - lstart[b0]; gbase[b0] = c ? atomicAdd(&bkt_cnt[b0], c) : 0; }
    if (b1 < NBKT) { int c = lstart[b1 + 1] - lstart[b1]; gbase[b1] = c ? atomicAdd(&bkt_cnt[b1], c) : 0; }
    lcount[tid] = lstart[tid];
    lcount[tid + 256] = lstart[tid + 256];
  }
  __syncthreads();

#pragma unroll
  for (int i = 0; i < EPB / 256; ++i) {
    int e = e0 + tid + i * 256;
    if (e >= E) continue;
    int2 v = ev[i];
    int r1 = gofs + v.y;
    u32 w1 = (u32)v.x | ((u32)(r1 & 511) << 20);
    int bk1 = r1 >> 9;
    int p = atomicAdd(&lcount[bk1], 1);
    ein[p] = w1; ebkt[p] = (u16)bk1;
    int r2 = gofs + v.x;
    u32 w2 = (u32)v.y | ((u32)(r2 & 511) << 20);
    int bk2 = r2 >> 9;
    p = atomicAdd(&lcount[bk2], 1);
    ein[p] = w2; ebkt[p] = (u16)bk2;
  }
  __syncthreads();

  int tot = lstart[512];
  for (int j = tid; j < tot; j += 256) {
    int bk = ebkt[j];
    u32 off = (u32)(gbase[bk] + (j - lstart[bk]));
    if (off < BKT_CAP) csr_tmp[(size_t)bk * BKT_CAP + off] = ein[j];
  }
}

// ---- Phase B1: per-bucket row counts -> rdeg only (coalesced) ----
__global__ void k_deg(const u32* __restrict__ csr_tmp, const int* __restrict__ bkt_cnt,
                      float* __restrict__ rdeg) {
  __shared__ int lcnt[512];
  int bk = blockIdx.x, tid = threadIdx.x;   // 512 threads
  lcnt[tid] = 0;
  __syncthreads();
  int cnt = min(bkt_cnt[bk], BKT_CAP);
  const u32* src = csr_tmp + (size_t)bk * BKT_CAP;
  for (int j = tid; j < cnt; j += 512)
    atomicAdd(&lcnt[(src[j] >> 20) & 511], 1);
  __syncthreads();
  int row = (bk << 9) + tid;
  if (row < N2_C) rdeg[row] = rsqrtf((float)(lcnt[tid] + 1));
}

// ---- bucket-base scan: exclusive sum of 391 bucket counts; also total ----
__global__ void k_scanb(const int* __restrict__ bkt_cnt, int* __restrict__ bbase,
                        int* __restrict__ row_start) {
  __shared__ int s[512];
  int tid = threadIdx.x;                    // 512 threads
  int v = (tid < NBKT) ? bkt_cnt[tid] : 0;
  s[tid] = v;
  __syncthreads();
  for (int off = 1; off < 512; off <<= 1) {
    int u = (tid >= off) ? s[tid - off] : 0;
    __syncthreads();
    s[tid] += u;
    __syncthreads();
  }
  if (tid < NBKT) bbase[tid] = s[tid] - v;  // exclusive
  if (tid == NBKT - 1) row_start[N2_C] = s[tid];  // grand total
}

// ---- Phase B2: per bucket, LDS count+scan -> row_start (coalesced) + sorted
// u32 CSR {src}. No global rdeg gather (k_fused does scalar rdeg loads).
__global__ __launch_bounds__(512) void k_csr_sort(
    const u32* __restrict__ csr_tmp, const int* __restrict__ bkt_cnt,
    const int* __restrict__ bbase, int* __restrict__ row_start,
    u32* __restrict__ csr) {
  __shared__ int lcnt[512];
  __shared__ int lofs[512];
  int bk = blockIdx.x, tid = threadIdx.x;   // 512 threads
  lcnt[tid] = 0;
  __syncthreads();
  int cnt = min(bkt_cnt[bk], BKT_CAP);
  int base = bbase[bk];
  const u32* srcp = csr_tmp + (size_t)bk * BKT_CAP;
  for (int j = tid; j < cnt; j += 512)
    atomicAdd(&lcnt[(srcp[j] >> 20) & 511], 1);
  __syncthreads();
  int own = lcnt[tid];
  lofs[tid] = own;
  __syncthreads();
  for (int off = 1; off < 512; off <<= 1) {
    int u = (tid >= off) ? lofs[tid - off] : 0;
    __syncthreads();
    lofs[tid] += u;
    __syncthreads();
  }
  int ex = lofs[tid] - own;
  int row = (bk << 9) + tid;
  if (row < N2_C) row_start[row] = base + ex;
  lcnt[tid] = ex;                           // reuse as cursors
  __syncthreads();
  for (int j = tid; j < cnt; j += 512) {
    u32 w = srcp[j];
    int dl = (w >> 20) & 511;
    int pos = atomicAdd(&lcnt[dl], 1);
    csr[base + pos] = w & 0x1FFFF;
  }
}

// emb (fp32 or bf16 per flag) -> packed bf16 x. 16 B out per thread.
__global__ void k_cvt_bf16(const void* __restrict__ s0, const void* __restrict__ s1,
                           u32* __restrict__ d0, u32* __restrict__ d1,
                           const int* __restrict__ flag, int n4) {
  int i = blockIdx.x * 256 + threadIdx.x;
  if (i >= n4) return;
  const void* src = blockIdx.y ? s1 : s0;
  u32* dst = blockIdx.y ? d1 : d0;
  uint4 o;
  if (*flag) {
    const float4* sf = (const float4*)src;
    float4 va = sf[2 * i], vb = sf[2 * i + 1];
    o.x = (u32)f2bf(va.x) | ((u32)f2bf(va.y) << 16);
    o.y = (u32)f2bf(va.z) | ((u32)f2bf(va.w) << 16);
    o.z = (u32)f2bf(vb.x) | ((u32)f2bf(vb.y) << 16);
    o.w = (u32)f2bf(vb.z) | ((u32)f2bf(vb.w) << 16);
  } else {
    o = ((const uint4*)src)[i];
  }
  ((uint4*)dst)[i] = o;
}

// Scalarized gather steps: csr entry + rdeg via scalar path, xin vector load.
#define G2(cp, t, a0, a1) { \
  u32 s0 = __builtin_amdgcn_readfirstlane(cp[t]); \
  u32 s1 = __builtin_amdgcn_readfirstlane(cp[(t) + 1]); \
  float r0 = rdb[s0], r1 = rdb[s1]; \
  u32 v0 = xin[(s0 << 6) | lane]; \
  u32 v1 = xin[(s1 << 6) | lane]; \
  a0 += r0 * bflo(v0) + r1 * bflo(v1); \
  a1 += r0 * bfhi(v0) + r1 * bfhi(v1); }
#define G1(cp, t, a0, a1) { \
  u32 s0 = __builtin_amdgcn_readfirstlane(cp[t]); \
  float r0 = rdb[s0]; \
  u32 v0 = xin[(s0 << 6) | lane]; \
  a0 += r0 * bflo(v0); a1 += r0 * bfhi(v0); }

// Fused GCN layer. 512 threads (8 waves), 32 rows/block. LDS = 40960 B exactly
// -> 4 blocks/CU x 8 waves = 32 waves/CU. Gather pairs two rows per wave with
// fully scalarized entry/rdeg/address path (VALU floor: 2 extracts + 2 FMAs).
// deg comes from row_start differences. If fout != null: fp32 direct out.
__global__ __launch_bounds__(512, 8) void k_fused(
    const int* __restrict__ row_start, const u32* __restrict__ csru,
    const u32* __restrict__ xin0, const u32* __restrict__ xin1,
    const float* __restrict__ rdeg, const void* __restrict__ W,
    const int* __restrict__ flag, u32* __restrict__ xout0, u32* __restrict__ xout1,
    float* __restrict__ fout0, float* __restrict__ fout1) {
  __shared__ __align__(16) u16 smem[128 * 128 + 32 * 128];  // 40960 B
  u16* sWt = smem;               // 128x128 bf16 W^T, swizzled (32 KB)
  u16* sA  = smem + 128 * 128;   // 32x128 bf16 A-tile, swizzled (8 KB)

  const int tid = threadIdx.x;
  const int row0 = blockIdx.x * 32;
  const int gofs = blockIdx.y * N_ENT_C;
  const u32* __restrict__ xin  = blockIdx.y ? xin1  : xin0;
  u32* __restrict__ xout       = blockIdx.y ? xout1 : xout0;
  float* __restrict__ fout     = blockIdx.y ? fout1 : fout0;
  const int* rsb = row_start + gofs;
  const float* rdb = rdeg + gofs;
  const int isf32 = *flag;

  // ---- stage W^T (bf16), swizzled: u32 word (n, k2) at n*64 + (k2 ^ ((n&7)<<2))
  {
    u32* sW32 = (u32*)sWt;
    const float* Wf = (const float*)W;
    const u16*   Wu = (const u16*)W;
    for (int i = tid; i < 64 * 128; i += 512) {
      int k2 = i >> 7;        // pair of k: 2*k2, 2*k2+1
      int n  = i & 127;
      u16 lo, hi;
      if (isf32) { lo = f2bf(Wf[(2 * k2) * 128 + n]); hi = f2bf(Wf[(2 * k2 + 1) * 128 + n]); }
      else       { lo = Wu[(2 * k2) * 128 + n];       hi = Wu[(2 * k2 + 1) * 128 + n]; }
      sW32[n * 64 + (k2 ^ ((n & 7) << 2))] = (u32)lo | ((u32)hi << 16);
    }
  }

  // ---- gather: wave w owns rows [w*4, w*4+4), processed as 2 pairs ----
  const int wave = tid >> 6, lane = tid & 63;
  for (int pq = 0; pq < 2; ++pq) {
    const int rlA = wave * 4 + 2 * pq, rlB = rlA + 1;
    const int rowA = row0 + rlA, rowB = row0 + rlB;
    // rows consecutive: 3 scalar loads give both extents (rowB+1 <= N_ENT valid:
    // row_start is over the concatenated graphs + total sentinel).
    int rsA = __builtin_amdgcn_readfirstlane(rsb[rowA]);
    int rsB = __builtin_amdgcn_readfirstlane(rsb[rowA + 1]);
    int reB = __builtin_amdgcn_readfirstlane(rsb[rowA + 2]);
    const int deA = rsB - rsA, deB = reB - rsB;
    const float rdA = rdb[rowA], rdB = rdb[rowB];
    const u32 vsA = xin[((u32)rowA << 6) | lane];   // self term, issued early
    const u32 vsB = xin[((u32)rowB << 6) | lane];
    const u32* cA = csru + rsA;
    const u32* cB = csru + rsB;
    float a0A = 0.f, a1A = 0.f, a0B = 0.f, a1B = 0.f;
    int tA = 0, tB = 0;
    // joint phase: two independent chains, 4 xin loads in flight
    while (tA + 1 < deA && tB + 1 < deB) {
      u32 iA0 = __builtin_amdgcn_readfirstlane(cA[tA]);
      u32 iA1 = __builtin_amdgcn_readfirstlane(cA[tA + 1]);
      u32 iB0 = __builtin_amdgcn_readfirstlane(cB[tB]);
      u32 iB1 = __builtin_amdgcn_readfirstlane(cB[tB + 1]);
      float rA0 = rdb[iA0], rA1 = rdb[iA1];
      float rB0 = rdb[iB0], rB1 = rdb[iB1];
      u32 uA0 = xin[(iA0 << 6) | lane];
      u32 uA1 = xin[(iA1 << 6) | lane];
      u32 uB0 = xin[(iB0 << 6) | lane];
      u32 uB1 = xin[(iB1 << 6) | lane];
      a0A += rA0 * bflo(uA0) + rA1 * bflo(uA1);
      a1A += rA0 * bfhi(uA0) + rA1 * bfhi(uA1);
      a0B += rB0 * bflo(uB0) + rB1 * bflo(uB1);
      a1B += rB0 * bfhi(uB0) + rB1 * bfhi(uB1);
      tA += 2; tB += 2;
    }
    // drains (one of the two rows typically has entries left)
    for (; tA + 3 < deA; tA += 4) { G2(cA, tA, a0A, a1A); G2(cA, tA + 2, a0A, a1A); }
    if (tA + 1 < deA) { G2(cA, tA, a0A, a1A); tA += 2; }
    if (tA < deA) G1(cA, tA, a0A, a1A);
    for (; tB + 3 < deB; tB += 4) { G2(cB, tB, a0B, a1B); G2(cB, tB + 2, a0B, a1B); }
    if (tB + 1 < deB) { G2(cB, tB, a0B, a1B); tB += 2; }
    if (tB < deB) G1(cB, tB, a0B, a1B);

    a0A = rdA * a0A + rdA * rdA * bflo(vsA);
    a1A = rdA * a1A + rdA * rdA * bfhi(vsA);
    a0B = rdB * a0B + rdB * rdB * bflo(vsB);
    a1B = rdB * a1B + rdB * rdB * bfhi(vsB);
    ((u32*)sA)[rlA * 64 + (lane ^ ((rlA & 7) << 2))] = (u32)f2bf(a0A) | ((u32)f2bf(a1A) << 16);
    ((u32*)sA)[rlB * 64 + (lane ^ ((rlB & 7) << 2))] = (u32)f2bf(a0B) | ((u32)f2bf(a1B) << 16);
  }
  __syncthreads();

  // ---- MFMA: 8 waves, wave -> 16 rows x 32 cols ----
  const int rows_h = (wave >> 2) * 16;   // 0 | 16
  const int col_q  = (wave & 3) * 32;    // 0 | 32 | 64 | 96
  const int m = lane & 15, q = lane >> 4;
  f32x4 acc[2];
  for (int ct = 0; ct < 2; ++ct) acc[ct] = (f32x4){0.f, 0.f, 0.f, 0.f};
#pragma unroll
  for (int kt = 0; kt < 4; ++kt) {
    int k0 = kt * 32 + q * 8;
    int ks = k0 ^ ((m & 7) << 3);        // same swizzle for A row and W^T rows
    bf16x8 a = *(const bf16x8*)&sA[(rows_h + m) * 128 + ks];
#pragma unroll
    for (int ct = 0; ct < 2; ++ct) {
      bf16x8 b = *(const bf16x8*)&sWt[(col_q + ct * 16 + m) * 128 + ks];
      acc[ct] = __builtin_amdgcn_mfma_f32_16x16x32_bf16(a, b, acc[ct], 0, 0, 0);
    }
  }
  __syncthreads();   // all waves done reading sWt/sA before C overwrites smem

  // ---- C (fp32) into LDS for coalesced epilogue ----
  float* sC = (float*)smem;              // 32 x 132 fp32 = 16896 B (fits 40 KB)
#pragma unroll
  for (int ct = 0; ct < 2; ++ct)
#pragma unroll
    for (int r = 0; r < 4; ++r)
      sC[(rows_h + q * 4 + r) * 132 + (col_q + ct * 16 + m)] = acc[ct][r];
  __syncthreads();

  // ---- epilogue: +residual, relu; fp32 direct out (final) or bf16 pack ----
  {
    int rowl = tid >> 4;                 // 0..31 (16 threads per row)
    int c0 = (tid & 15) * 8;             // 8 cols per thread
    int row = row0 + rowl;
    size_t goff = (size_t)row * 64 + (c0 >> 1);  // in u32 units
    const u32* resp = xin + goff;
    if (fout) {
      float* op = fout + (size_t)row * 128 + c0;
#pragma unroll
      for (int u2 = 0; u2 < 2; ++u2) {
        u32 rv0 = resp[2 * u2], rv1 = resp[2 * u2 + 1];
        f32x4 f;
        f[0] = fmaxf(sC[rowl * 132 + c0 + 4 * u2    ] + bflo(rv0), 0.f);
        f[1] = fmaxf(sC[rowl * 132 + c0 + 4 * u2 + 1] + bfhi(rv0), 0.f);
        f[2] = fmaxf(sC[rowl * 132 + c0 + 4 * u2 + 2] + bflo(rv1), 0.f);
        f[3] = fmaxf(sC[rowl * 132 + c0 + 4 * u2 + 3] + bfhi(rv1), 0.f);
        __builtin_nontemporal_store(f, (f32x4*)(op + 4 * u2));
      }
    } else {
      u32 ov[4];
#pragma unroll
      for (int u = 0; u < 4; ++u) {
        u32 rv = resp[u];
        float lo = fmaxf(sC[rowl * 132 + c0 + 2 * u]     + bflo(rv), 0.f);
        float hi = fmaxf(sC[rowl * 132 + c0 + 2 * u + 1] + bfhi(rv), 0.f);
        ov[u] = (u32)f2bf(lo) | ((u32)f2bf(hi) << 16);
      }
      uint4* op = (uint4*)(xout + goff);
      op[0] = make_uint4(ov[0], ov[1], ov[2], ov[3]);
    }
  }
}

// Seed outputs: copy fp32 rows from out_ent (already final fp32).
__global__ void k_out_seed(const float4* __restrict__ ea, const float4* __restrict__ eb,
                           const int* __restrict__ sa, const int* __restrict__ sb,
                           float4* __restrict__ oa, float4* __restrict__ ob, int total4) {
  int t = blockIdx.x * 256 + threadIdx.x;
  if (t >= total4) return;
  const float4* e = blockIdx.y ? eb : ea;
  const int* seeds = blockIdx.y ? sb : sa;
  float4* o = blockIdx.y ? ob : oa;
  int s = t >> 5, w = t & 31;            // 32 float4 per row
  o[t] = e[((size_t)seeds[s] << 5) | w];
}

extern "C" void kernel_launch(void* const* d_in, const int* in_sizes, int n_in,
                              void* d_out, int out_size, void* d_ws, size_t ws_size,
                              hipStream_t stream) {
  const int*  sr_seeds = (const int*)d_in[0];
  const int*  tg_seeds = (const int*)d_in[1];
  // d_in[2], d_in[3]: triples_* — unused by the reference.
  const void* emb_sr   = d_in[4];
  const void* emb_tg   = d_in[5];
  const int*  edges_sr = (const int*)d_in[6];
  const int*  edges_tg = (const int*)d_in[7];
  const void* W1       = d_in[8];
  const void* W2       = d_in[9];
  float* out = (float*)d_out;

  const int nd = N_ENT_C * DIM_C;  // 12,800,000

  // ws layout (~86.5 MB of >=102.8 MB proven):
  u16* x_A       = (u16*)d_ws;                    // 25.6 MB (cvt out sr, L1 in)
  u16* x_B       = x_A + (size_t)nd;              // 25.6 MB (cvt out tg, L1 in)
  float* ws_rdeg = (float*)(x_B + (size_t)nd);    // 800 KB (2N)
  int* ws_flag   = (int*)(ws_rdeg + N2_C);        // 256 B
  int* row_start = ws_flag + 64;                  // 800 KB (2N + 1, padded)
  int* bkt_cnt   = row_start + N2_C + 64;         // 2 KB
  int* bbase     = bkt_cnt + 512;                 // 2 KB
  u32* csr       = (u32*)(bbase + 512);           // 8 MB (2M u32 {src})
  u32* csr_tmp   = csr + (size_t)4 * N_EDGE_C;    // 12.8 MB, dead after sort
  u16* x_C       = (u16*)csr_tmp;                 // 25.6 MB overlay (L1-sr out, L2 in)

  float* out_seed_sr = out;
  float* out_seed_tg = out + (size_t)N_SEED_C * DIM_C;
  float* out_ent_sr  = out + (size_t)2 * N_SEED_C * DIM_C;
  float* out_ent_tg  = out_ent_sr + (size_t)nd;

  // x_D (L1 out tg) lives in out_ent_sr region; consumed by L2-tg BEFORE
  // L2-sr overwrites that region with fp32 (in-order stream).
  u16* x_D = (u16*)out_ent_sr;

  k_detect<<<1, 256, 0, stream>>>((const u32*)emb_sr, ws_flag, bkt_cnt);

  // ---- binned CSR build (both graphs concatenated) ----
  dim3 agrid((N_EDGE_C + EPB - 1) / EPB, 2);      // 245 x 2
  k_fill_binned<<<agrid, 256, 0, stream>>>((const int2*)edges_sr, (const int2*)edges_tg,
                                           bkt_cnt, csr_tmp, N_EDGE_C);
  k_deg  <<<NBKT, 512, 0, stream>>>(csr_tmp, bkt_cnt, ws_rdeg);
  k_scanb<<<1, 512, 0, stream>>>(bkt_cnt, bbase, row_start);
  k_csr_sort<<<NBKT, 512, 0, stream>>>(csr_tmp, bkt_cnt, bbase, row_start, csr);

  // ---- embeddings -> bf16 (both graphs, one dispatch, 16B/thread) ----
  dim3 cgrid((nd / 8 + 255) / 256, 2);
  k_cvt_bf16<<<cgrid, 256, 0, stream>>>(emb_sr, emb_tg, (u32*)x_A, (u32*)x_B, ws_flag, nd / 8);

  const int NBF = N_ENT_C / 32;                   // 3125

  // ---- L1: A,B -> C,D (bf16), both graphs in one dispatch ----
  dim3 f2grid(NBF, 2);
  k_fused<<<f2grid, 512, 0, stream>>>(row_start, csr, (const u32*)x_A, (const u32*)x_B,
                                      ws_rdeg, W1, ws_flag, (u32*)x_C, (u32*)x_D,
                                      nullptr, nullptr);

  // ---- L2-tg first (reads x_D in out_ent_sr region), writes fp32 out_ent_tg ----
  k_fused<<<dim3(NBF, 1), 512, 0, stream>>>(row_start + N_ENT_C, csr,
                                            (const u32*)x_D, nullptr, ws_rdeg + N_ENT_C,
                                            W2, ws_flag, nullptr, nullptr,
                                            out_ent_tg, nullptr);
  // ---- L2-sr: reads x_C (ws), writes fp32 out_ent_sr (clobbers dead x_D) ----
  k_fused<<<dim3(NBF, 1), 512, 0, stream>>>(row_start, csr,
                                            (const u32*)x_C, nullptr, ws_rdeg,
                                            W2, ws_flag, nullptr, nullptr,
                                            out_ent_sr, nullptr);

  // ---- seed outputs: fp32 row copies from out_ent ----
  dim3 sgrid((N_SEED_C * 32 + 255) / 256, 2);
  k_out_seed<<<sgrid, 256, 0, stream>>>((const float4*)out_ent_sr, (const float4*)out_ent_tg,
                                        sr_seeds, tg_seeds,
                                        (float4*)out_seed_sr, (float4*)out_seed_tg,
                                        N_SEED_C * 32);
}

// Round 10
// 506.344 us; speedup vs baseline: 1.0934x; 1.0338x over previous
//
#include <hip/hip_runtime.h>
#include <hip/hip_bf16.h>

#define N_ENT_C   100000
#define N_EDGE_C  500000
#define N_SEED_C  10000
#define DIM_C     128

#define N2_C      (2 * N_ENT_C)     // concat rows (both graphs)
#define NBKT      391               // ceil(N2 / 512)
#define BKT_CAP   8192              // entries per bucket (mean 5120, 43 sigma safe)
#define EPB       2048              // edges per block in phase A
#define NB_FILL   ((N_EDGE_C + EPB - 1) / EPB)   // 245

typedef unsigned int   u32;
typedef unsigned short u16;
typedef __attribute__((ext_vector_type(8))) short bf16x8;
typedef __attribute__((ext_vector_type(4))) float f32x4;

__device__ __forceinline__ float bflo(u32 v) { return __uint_as_float(v << 16); }
__device__ __forceinline__ float bfhi(u32 v) { return __uint_as_float(v & 0xFFFF0000u); }
__device__ __forceinline__ u16 f2bf(float f) {       // RNE
  u32 u = __float_as_uint(f);
  u += 0x7FFFu + ((u >> 16) & 1u);
  return (u16)(u >> 16);
}

// Detect fp32 vs packed bf16 input; also zero the bucket counters.
__global__ void k_detect(const u32* __restrict__ words, int* __restrict__ flag,
                         int* __restrict__ bkt_cnt) {
  int tid = threadIdx.x;
  bkt_cnt[tid] = 0;
  bkt_cnt[tid + 256] = 0;
  if (tid == 0) {
    int cnt = 0;
    for (int i = 0; i < 64; ++i) {
      u32 e = (words[i] >> 7) & 0xFF;
      cnt += (e < 96) ? 1 : 0;
    }
    *flag = (cnt >= 8) ? 1 : 0;  // 1 = fp32, 0 = bf16
  }
}

// ---- Merged: edge binning (blocks.x < NB_FILL) + embedding cvt (rest) ----
// Overlaps the atomic/latency-bound binning with the BW-bound convert.
// Bin entry: u32 = src | (dlocal << 20).
__global__ __launch_bounds__(256, 4) void k_build(
    const int2* __restrict__ ea, const int2* __restrict__ eb,
    int* __restrict__ bkt_cnt, u32* __restrict__ csr_tmp, int E,
    const void* __restrict__ s0, const void* __restrict__ s1,
    u32* __restrict__ d0, u32* __restrict__ d1,
    const int* __restrict__ flag, int n4) {
  __shared__ u32 ein[2 * EPB];        // 16 KB
  __shared__ u16 ebkt[2 * EPB];       //  8 KB
  __shared__ int lcount[512];         // counts, then cursors
  __shared__ int lstart[513];
  __shared__ int gbase[512];
  __shared__ int ssc[256];

  const int tid = threadIdx.x;

  if (blockIdx.x >= NB_FILL) {
    // ---- embedding convert part: 16 B out per thread ----
    int i = (blockIdx.x - NB_FILL) * 256 + tid;
    if (i >= n4) return;
    const void* src = blockIdx.y ? s1 : s0;
    u32* dst = blockIdx.y ? d1 : d0;
    uint4 o;
    if (*flag) {
      const float4* sf = (const float4*)src;
      float4 va = sf[2 * i], vb = sf[2 * i + 1];
      o.x = (u32)f2bf(va.x) | ((u32)f2bf(va.y) << 16);
      o.y = (u32)f2bf(va.z) | ((u32)f2bf(va.w) << 16);
      o.z = (u32)f2bf(vb.x) | ((u32)f2bf(vb.y) << 16);
      o.w = (u32)f2bf(vb.z) | ((u32)f2bf(vb.w) << 16);
    } else {
      o = ((const uint4*)src)[i];
    }
    ((uint4*)dst)[i] = o;
    return;
  }

  // ---- binning part ----
  const int gofs = blockIdx.y ? N_ENT_C : 0;
  const int2* ed = blockIdx.y ? eb : ea;
  const int e0 = blockIdx.x * EPB;

  lcount[tid] = 0; lcount[tid + 256] = 0;
  __syncthreads();

  int2 ev[EPB / 256];
#pragma unroll
  for (int i = 0; i < EPB / 256; ++i) {
    int e = e0 + tid + i * 256;
    int2 v = (e < E) ? ed[e] : make_int2(0, 0);
    ev[i] = v;
    if (e < E) {
      atomicAdd(&lcount[(gofs + v.y) >> 9], 1);
      atomicAdd(&lcount[(gofs + v.x) >> 9], 1);
    }
  }
  __syncthreads();

  int a = lcount[2 * tid], b = lcount[2 * tid + 1];
  int ts = a + b;
  ssc[tid] = ts;
  __syncthreads();
  for (int off = 1; off < 256; off <<= 1) {
    int v = (tid >= off) ? ssc[tid - off] : 0;
    __syncthreads();
    ssc[tid] += v;
    __syncthreads();
  }
  int ex = ssc[tid] - ts;
  lstart[2 * tid] = ex;
  lstart[2 * tid + 1] = ex + a;
  if (tid == 255) lstart[512] = ssc[255];
  __syncthreads();

  {
    int b0 = 2 * tid, b1 = 2 * tid + 1;
    if (b0 < NBKT) { int c = lstart[b0 + 1] - lstart[b0]; gbase[b0] = c ? atomicAdd(&bkt_cnt[b0], c) : 0; }
    if (b1 < NBKT) { int c = lstart[b1 + 1] - lstart[b1]; gbase[b1] = c ? atomicAdd(&bkt_cnt[b1], c) : 0; }
    lcount[tid] = lstart[tid];
    lcount[tid + 256] = lstart[tid + 256];
  }
  __syncthreads();

#pragma unroll
  for (int i = 0; i < EPB / 256; ++i) {
    int e = e0 + tid + i * 256;
    if (e >= E) continue;
    int2 v = ev[i];
    int r1 = gofs + v.y;
    u32 w1 = (u32)v.x | ((u32)(r1 & 511) << 20);
    int bk1 = r1 >> 9;
    int p = atomicAdd(&lcount[bk1], 1);
    ein[p] = w1; ebkt[p] = (u16)bk1;
    int r2 = gofs + v.x;
    u32 w2 = (u32)v.y | ((u32)(r2 & 511) << 20);
    int bk2 = r2 >> 9;
    p = atomicAdd(&lcount[bk2], 1);
    ein[p] = w2; ebkt[p] = (u16)bk2;
  }
  __syncthreads();

  int tot = lstart[512];
  for (int j = tid; j < tot; j += 256) {
    int bk = ebkt[j];
    u32 off = (u32)(gbase[bk] + (j - lstart[bk]));
    if (off < BKT_CAP) csr_tmp[(size_t)bk * BKT_CAP + off] = ein[j];
  }
}

// ---- bucket-base scan: exclusive sum of 391 bucket counts; also total ----
__global__ void k_scanb(const int* __restrict__ bkt_cnt, int* __restrict__ bbase,
                        int* __restrict__ row_start) {
  __shared__ int s[512];
  int tid = threadIdx.x;                    // 512 threads
  int v = (tid < NBKT) ? bkt_cnt[tid] : 0;
  s[tid] = v;
  __syncthreads();
  for (int off = 1; off < 512; off <<= 1) {
    int u = (tid >= off) ? s[tid - off] : 0;
    __syncthreads();
    s[tid] += u;
    __syncthreads();
  }
  if (tid < NBKT) bbase[tid] = s[tid] - v;  // exclusive
  if (tid == NBKT - 1) row_start[N2_C] = s[tid];  // grand total
}

// ---- Phase B2: per bucket, LDS count+scan -> row_start + rdeg (coalesced)
// + sorted u32 CSR {src}. (rdeg folded here; k_deg kernel deleted.)
__global__ __launch_bounds__(512) void k_csr_sort(
    const u32* __restrict__ csr_tmp, const int* __restrict__ bkt_cnt,
    const int* __restrict__ bbase, int* __restrict__ row_start,
    float* __restrict__ rdeg, u32* __restrict__ csr) {
  __shared__ int lcnt[512];
  __shared__ int lofs[512];
  int bk = blockIdx.x, tid = threadIdx.x;   // 512 threads
  lcnt[tid] = 0;
  __syncthreads();
  int cnt = min(bkt_cnt[bk], BKT_CAP);
  int base = bbase[bk];
  const u32* srcp = csr_tmp + (size_t)bk * BKT_CAP;
  for (int j = tid; j < cnt; j += 512)
    atomicAdd(&lcnt[(srcp[j] >> 20) & 511], 1);
  __syncthreads();
  int own = lcnt[tid];
  lofs[tid] = own;
  __syncthreads();
  for (int off = 1; off < 512; off <<= 1) {
    int u = (tid >= off) ? lofs[tid - off] : 0;
    __syncthreads();
    lofs[tid] += u;
    __syncthreads();
  }
  int ex = lofs[tid] - own;
  int row = (bk << 9) + tid;
  if (row < N2_C) {
    row_start[row] = base + ex;
    rdeg[row] = rsqrtf((float)(own + 1));
  }
  lcnt[tid] = ex;                           // reuse as cursors
  __syncthreads();
  for (int j = tid; j < cnt; j += 512) {
    u32 w = srcp[j];
    int dl = (w >> 20) & 511;
    int pos = atomicAdd(&lcnt[dl], 1);
    csr[base + pos] = w & 0x1FFFF;
  }
}

// Scalarized gather steps: csr entry + rdeg via scalar path, xin vector load.
#define G2(cp, t, a0, a1) { \
  u32 s0 = __builtin_amdgcn_readfirstlane(cp[t]); \
  u32 s1 = __builtin_amdgcn_readfirstlane(cp[(t) + 1]); \
  float r0 = rdb[s0], r1 = rdb[s1]; \
  u32 v0 = xin[(s0 << 6) | lane]; \
  u32 v1 = xin[(s1 << 6) | lane]; \
  a0 += r0 * bflo(v0) + r1 * bflo(v1); \
  a1 += r0 * bfhi(v0) + r1 * bfhi(v1); }
#define G1(cp, t, a0, a1) { \
  u32 s0 = __builtin_amdgcn_readfirstlane(cp[t]); \
  float r0 = rdb[s0]; \
  u32 v0 = xin[(s0 << 6) | lane]; \
  a0 += r0 * bflo(v0); a1 += r0 * bfhi(v0); }

// Fused GCN layer. 512 threads (8 waves), 32 rows/block. LDS = 40960 B exactly
// -> 4 blocks/CU x 8 waves = 32 waves/CU. Gather is LLC-fabric-bound (~2.6 TB/s
// at the ~300 MB XCD-replication fetch floor) — measured invariant vs occupancy,
// ILP, and VALU. deg from row_start differences. If fout != null: fp32 out.
__global__ __launch_bounds__(512, 8) void k_fused(
    const int* __restrict__ row_start, const u32* __restrict__ csru,
    const u32* __restrict__ xin0, const u32* __restrict__ xin1,
    const float* __restrict__ rdeg, const void* __restrict__ W,
    const int* __restrict__ flag, u32* __restrict__ xout0, u32* __restrict__ xout1,
    float* __restrict__ fout0, float* __restrict__ fout1) {
  __shared__ __align__(16) u16 smem[128 * 128 + 32 * 128];  // 40960 B
  u16* sWt = smem;               // 128x128 bf16 W^T, swizzled (32 KB)
  u16* sA  = smem + 128 * 128;   // 32x128 bf16 A-tile, swizzled (8 KB)

  const int tid = threadIdx.x;
  const int row0 = blockIdx.x * 32;
  const int gofs = blockIdx.y * N_ENT_C;
  const u32* __restrict__ xin  = blockIdx.y ? xin1  : xin0;
  u32* __restrict__ xout       = blockIdx.y ? xout1 : xout0;
  float* __restrict__ fout     = blockIdx.y ? fout1 : fout0;
  const int* rsb = row_start + gofs;
  const float* rdb = rdeg + gofs;
  const int isf32 = *flag;

  // ---- stage W^T (bf16), swizzled: u32 word (n, k2) at n*64 + (k2 ^ ((n&7)<<2))
  {
    u32* sW32 = (u32*)sWt;
    const float* Wf = (const float*)W;
    const u16*   Wu = (const u16*)W;
    for (int i = tid; i < 64 * 128; i += 512) {
      int k2 = i >> 7;        // pair of k: 2*k2, 2*k2+1
      int n  = i & 127;
      u16 lo, hi;
      if (isf32) { lo = f2bf(Wf[(2 * k2) * 128 + n]); hi = f2bf(Wf[(2 * k2 + 1) * 128 + n]); }
      else       { lo = Wu[(2 * k2) * 128 + n];       hi = Wu[(2 * k2 + 1) * 128 + n]; }
      sW32[n * 64 + (k2 ^ ((n & 7) << 2))] = (u32)lo | ((u32)hi << 16);
    }
  }

  // ---- gather: wave w owns rows [w*4, w*4+4), processed as 2 pairs ----
  const int wave = tid >> 6, lane = tid & 63;
  for (int pq = 0; pq < 2; ++pq) {
    const int rlA = wave * 4 + 2 * pq, rlB = rlA + 1;
    const int rowA = row0 + rlA, rowB = row0 + rlB;
    int rsA = __builtin_amdgcn_readfirstlane(rsb[rowA]);
    int rsB = __builtin_amdgcn_readfirstlane(rsb[rowA + 1]);
    int reB = __builtin_amdgcn_readfirstlane(rsb[rowA + 2]);
    const int deA = rsB - rsA, deB = reB - rsB;
    const float rdA = rdb[rowA], rdB = rdb[rowB];
    const u32 vsA = xin[((u32)rowA << 6) | lane];   // self term, issued early
    const u32 vsB = xin[((u32)rowB << 6) | lane];
    const u32* cA = csru + rsA;
    const u32* cB = csru + rsB;
    float a0A = 0.f, a1A = 0.f, a0B = 0.f, a1B = 0.f;
    int tA = 0, tB = 0;
    // joint phase: two independent chains, 4 xin loads in flight
    while (tA + 1 < deA && tB + 1 < deB) {
      u32 iA0 = __builtin_amdgcn_readfirstlane(cA[tA]);
      u32 iA1 = __builtin_amdgcn_readfirstlane(cA[tA + 1]);
      u32 iB0 = __builtin_amdgcn_readfirstlane(cB[tB]);
      u32 iB1 = __builtin_amdgcn_readfirstlane(cB[tB + 1]);
      float rA0 = rdb[iA0], rA1 = rdb[iA1];
      float rB0 = rdb[iB0], rB1 = rdb[iB1];
      u32 uA0 = xin[(iA0 << 6) | lane];
      u32 uA1 = xin[(iA1 << 6) | lane];
      u32 uB0 = xin[(iB0 << 6) | lane];
      u32 uB1 = xin[(iB1 << 6) | lane];
      a0A += rA0 * bflo(uA0) + rA1 * bflo(uA1);
      a1A += rA0 * bfhi(uA0) + rA1 * bfhi(uA1);
      a0B += rB0 * bflo(uB0) + rB1 * bflo(uB1);
      a1B += rB0 * bfhi(uB0) + rB1 * bfhi(uB1);
      tA += 2; tB += 2;
    }
    // drains (one of the two rows typically has entries left)
    for (; tA + 3 < deA; tA += 4) { G2(cA, tA, a0A, a1A); G2(cA, tA + 2, a0A, a1A); }
    if (tA + 1 < deA) { G2(cA, tA, a0A, a1A); tA += 2; }
    if (tA < deA) G1(cA, tA, a0A, a1A);
    for (; tB + 3 < deB; tB += 4) { G2(cB, tB, a0B, a1B); G2(cB, tB + 2, a0B, a1B); }
    if (tB + 1 < deB) { G2(cB, tB, a0B, a1B); tB += 2; }
    if (tB < deB) G1(cB, tB, a0B, a1B);

    a0A = rdA * a0A + rdA * rdA * bflo(vsA);
    a1A = rdA * a1A + rdA * rdA * bfhi(vsA);
    a0B = rdB * a0B + rdB * rdB * bflo(vsB);
    a1B = rdB * a1B + rdB * rdB * bfhi(vsB);
    ((u32*)sA)[rlA * 64 + (lane ^ ((rlA & 7) << 2))] = (u32)f2bf(a0A) | ((u32)f2bf(a1A) << 16);
    ((u32*)sA)[rlB * 64 + (lane ^ ((rlB & 7) << 2))] = (u32)f2bf(a0B) | ((u32)f2bf(a1B) << 16);
  }
  __syncthreads();

  // ---- MFMA: 8 waves, wave -> 16 rows x 32 cols ----
  const int rows_h = (wave >> 2) * 16;   // 0 | 16
  const int col_q  = (wave & 3) * 32;    // 0 | 32 | 64 | 96
  const int m = lane & 15, q = lane >> 4;
  f32x4 acc[2];
  for (int ct = 0; ct < 2; ++ct) acc[ct] = (f32x4){0.f, 0.f, 0.f, 0.f};
#pragma unroll
  for (int kt = 0; kt < 4; ++kt) {
    int k0 = kt * 32 + q * 8;
    int ks = k0 ^ ((m & 7) << 3);        // same swizzle for A row and W^T rows
    bf16x8 a = *(const bf16x8*)&sA[(rows_h + m) * 128 + ks];
#pragma unroll
    for (int ct = 0; ct < 2; ++ct) {
      bf16x8 b = *(const bf16x8*)&sWt[(col_q + ct * 16 + m) * 128 + ks];
      acc[ct] = __builtin_amdgcn_mfma_f32_16x16x32_bf16(a, b, acc[ct], 0, 0, 0);
    }
  }
  __syncthreads();   // all waves done reading sWt/sA before C overwrites smem

  // ---- C (fp32) into LDS for coalesced epilogue ----
  float* sC = (float*)smem;              // 32 x 132 fp32 = 16896 B (fits 40 KB)
#pragma unroll
  for (int ct = 0; ct < 2; ++ct)
#pragma unroll
    for (int r = 0; r < 4; ++r)
      sC[(rows_h + q * 4 + r) * 132 + (col_q + ct * 16 + m)] = acc[ct][r];
  __syncthreads();

  // ---- epilogue: +residual, relu; fp32 direct out (final) or bf16 pack ----
  {
    int rowl = tid >> 4;                 // 0..31 (16 threads per row)
    int c0 = (tid & 15) * 8;             // 8 cols per thread
    int row = row0 + rowl;
    size_t goff = (size_t)row * 64 + (c0 >> 1);  // in u32 units
    const u32* resp = xin + goff;
    if (fout) {
      float* op = fout + (size_t)row * 128 + c0;
#pragma unroll
      for (int u2 = 0; u2 < 2; ++u2) {
        u32 rv0 = resp[2 * u2], rv1 = resp[2 * u2 + 1];
        f32x4 f;
        f[0] = fmaxf(sC[rowl * 132 + c0 + 4 * u2    ] + bflo(rv0), 0.f);
        f[1] = fmaxf(sC[rowl * 132 + c0 + 4 * u2 + 1] + bfhi(rv0), 0.f);
        f[2] = fmaxf(sC[rowl * 132 + c0 + 4 * u2 + 2] + bflo(rv1), 0.f);
        f[3] = fmaxf(sC[rowl * 132 + c0 + 4 * u2 + 3] + bfhi(rv1), 0.f);
        __builtin_nontemporal_store(f, (f32x4*)(op + 4 * u2));
      }
    } else {
      u32 ov[4];
#pragma unroll
      for (int u = 0; u < 4; ++u) {
        u32 rv = resp[u];
        float lo = fmaxf(sC[rowl * 132 + c0 + 2 * u]     + bflo(rv), 0.f);
        float hi = fmaxf(sC[rowl * 132 + c0 + 2 * u + 1] + bfhi(rv), 0.f);
        ov[u] = (u32)f2bf(lo) | ((u32)f2bf(hi) << 16);
      }
      uint4* op = (uint4*)(xout + goff);
      op[0] = make_uint4(ov[0], ov[1], ov[2], ov[3]);
    }
  }
}

// Seed outputs: copy fp32 rows from out_ent (already final fp32).
__global__ void k_out_seed(const float4* __restrict__ ea, const float4* __restrict__ eb,
                           const int* __restrict__ sa, const int* __restrict__ sb,
                           float4* __restrict__ oa, float4* __restrict__ ob, int total4) {
  int t = blockIdx.x * 256 + threadIdx.x;
  if (t >= total4) return;
  const float4* e = blockIdx.y ? eb : ea;
  const int* seeds = blockIdx.y ? sb : sa;
  float4* o = blockIdx.y ? ob : oa;
  int s = t >> 5, w = t & 31;            // 32 float4 per row
  o[t] = e[((size_t)seeds[s] << 5) | w];
}

extern "C" void kernel_launch(void* const* d_in, const int* in_sizes, int n_in,
                              void* d_out, int out_size, void* d_ws, size_t ws_size,
                              hipStream_t stream) {
  const int*  sr_seeds = (const int*)d_in[0];
  const int*  tg_seeds = (const int*)d_in[1];
  // d_in[2], d_in[3]: triples_* — unused by the reference.
  const void* emb_sr   = d_in[4];
  const void* emb_tg   = d_in[5];
  const int*  edges_sr = (const int*)d_in[6];
  const int*  edges_tg = (const int*)d_in[7];
  const void* W1       = d_in[8];
  const void* W2       = d_in[9];
  float* out = (float*)d_out;

  const int nd = N_ENT_C * DIM_C;  // 12,800,000

  // ws layout (~86.5 MB of >=102.8 MB proven):
  u16* x_A       = (u16*)d_ws;                    // 25.6 MB (cvt out sr, L1 in)
  u16* x_B       = x_A + (size_t)nd;              // 25.6 MB (cvt out tg, L1 in)
  float* ws_rdeg = (float*)(x_B + (size_t)nd);    // 800 KB (2N)
  int* ws_flag   = (int*)(ws_rdeg + N2_C);        // 256 B
  int* row_start = ws_flag + 64;                  // 800 KB (2N + 1, padded)
  int* bkt_cnt   = row_start + N2_C + 64;         // 2 KB
  int* bbase     = bkt_cnt + 512;                 // 2 KB
  u32* csr       = (u32*)(bbase + 512);           // 8 MB (2M u32 {src})
  u32* csr_tmp   = csr + (size_t)4 * N_EDGE_C;    // 12.8 MB, dead after sort
  u16* x_C       = (u16*)csr_tmp;                 // 25.6 MB overlay (L1-sr out, L2 in)

  float* out_seed_sr = out;
  float* out_seed_tg = out + (size_t)N_SEED_C * DIM_C;
  float* out_ent_sr  = out + (size_t)2 * N_SEED_C * DIM_C;
  float* out_ent_tg  = out_ent_sr + (size_t)nd;

  // x_D (L1 out tg) lives in out_ent_sr region; consumed by L2-tg BEFORE
  // L2-sr overwrites that region with fp32 (in-order stream).
  u16* x_D = (u16*)out_ent_sr;

  k_detect<<<1, 256, 0, stream>>>((const u32*)emb_sr, ws_flag, bkt_cnt);

  // ---- merged binning + embedding-cvt (both graphs; independent work) ----
  dim3 bgrid(NB_FILL + nd / 8 / 256, 2);          // 245 + 6250 = 6495 x 2
  k_build<<<bgrid, 256, 0, stream>>>((const int2*)edges_sr, (const int2*)edges_tg,
                                     bkt_cnt, csr_tmp, N_EDGE_C,
                                     emb_sr, emb_tg, (u32*)x_A, (u32*)x_B,
                                     ws_flag, nd / 8);
  k_scanb<<<1, 512, 0, stream>>>(bkt_cnt, bbase, row_start);
  k_csr_sort<<<NBKT, 512, 0, stream>>>(csr_tmp, bkt_cnt, bbase, row_start, ws_rdeg, csr);

  const int NBF = N_ENT_C / 32;                   // 3125

  // ---- L1: A,B -> C,D (bf16), both graphs in one dispatch ----
  dim3 f2grid(NBF, 2);
  k_fused<<<f2grid, 512, 0, stream>>>(row_start, csr, (const u32*)x_A, (const u32*)x_B,
                                      ws_rdeg, W1, ws_flag, (u32*)x_C, (u32*)x_D,
                                      nullptr, nullptr);

  // ---- L2-tg first (reads x_D in out_ent_sr region), writes fp32 out_ent_tg ----
  k_fused<<<dim3(NBF, 1), 512, 0, stream>>>(row_start + N_ENT_C, csr,
                                            (const u32*)x_D, nullptr, ws_rdeg + N_ENT_C,
                                            W2, ws_flag, nullptr, nullptr,
                                            out_ent_tg, nullptr);
  // ---- L2-sr: reads x_C (ws), writes fp32 out_ent_sr (clobbers dead x_D) ----
  k_fused<<<dim3(NBF, 1), 512, 0, stream>>>(row_start, csr,
                                            (const u32*)x_C, nullptr, ws_rdeg,
                                            W2, ws_flag, nullptr, nullptr,
                                            out_ent_sr, nullptr);

  // ---- seed outputs: fp32 row copies from out_ent ----
  dim3 sgrid((N_SEED_C * 32 + 255) / 256, 2);
  k_out_seed<<<sgrid, 256, 0, stream>>>((const float4*)out_ent_sr, (const float4*)out_ent_tg,
                                        sr_seeds, tg_seeds,
                                        (float4*)out_seed_sr, (float4*)out_seed_tg,
                                        N_SEED_C * 32);
}